// Round 2
// baseline (626.501 us; speedup 1.0000x reference)
//
#include <hip/hip_runtime.h>
#include <hip/hip_bf16.h>

namespace {

constexpr int kS = 4097;      // sequence incl. CLS
constexpr int kL = 4096;      // patch tokens
constexpr int kE = 768;
constexpr int kH = 12;
constexpr int kD = 64;
constexpr int kQKVN = 2304;
constexpr int kDil = 4;
constexpr float kScale = 0.125f;  // 1/sqrt(64)

typedef short short8 __attribute__((ext_vector_type(8)));
typedef float f32x4 __attribute__((ext_vector_type(4)));

__device__ inline short f2bf(float x) {
  __hip_bfloat16 b = __float2bfloat16(x);
  return *reinterpret_cast<short*>(&b);
}

// Load 8 consecutive fp32, convert to a bf16x8 MFMA fragment (two f32x4 loads).
__device__ inline short8 load_frag8(const float* __restrict__ p) {
  f32x4 lo = *reinterpret_cast<const f32x4*>(p);
  f32x4 hi = *reinterpret_cast<const f32x4*>(p + 4);
  short8 r;
#pragma unroll
  for (int j = 0; j < 4; ++j) {
    r[j] = f2bf(lo[j]);
    r[j + 4] = f2bf(hi[j]);
  }
  return r;
}

// C[M][N](f32) = A[M][K](f32) * W[N][K]^T(f32) + bias(f32); K%32==0, N%128==0.
// fp32 in/out, bf16 MFMA compute (fp32 accum). One block = 4 waves in N; each
// wave owns a 32x32 tile (2x2 fragments of 16x16x32). Correctness-first build.
__global__ __launch_bounds__(256) void gemm_wt_kernel(const float* __restrict__ A,
                                                      const float* __restrict__ W,
                                                      const float* __restrict__ bias,
                                                      float* __restrict__ C,
                                                      int M, int N, int K) {
  const int wave = threadIdx.x >> 6;
  const int lane = threadIdx.x & 63;
  const int m0 = blockIdx.x * 32;
  const int n0 = blockIdx.y * 128 + wave * 32;
  const int lrow = lane & 15;
  const int kgrp = (lane >> 4) << 3;  // 8 contiguous K elems per lane-group

  int arow[2];
  for (int mi = 0; mi < 2; ++mi) {
    int r = m0 + mi * 16 + lrow;
    arow[mi] = r < M ? r : M - 1;  // clamp for edge tile; stores are guarded
  }

  f32x4 acc[2][2] = {};

  for (int k = 0; k < K; k += 32) {
    short8 a[2], b[2];
    for (int mi = 0; mi < 2; ++mi)
      a[mi] = load_frag8(A + (size_t)arow[mi] * K + k + kgrp);
    for (int ni = 0; ni < 2; ++ni)
      b[ni] = load_frag8(W + (size_t)(n0 + ni * 16 + lrow) * K + k + kgrp);
    for (int mi = 0; mi < 2; ++mi)
      for (int ni = 0; ni < 2; ++ni)
        acc[mi][ni] = __builtin_amdgcn_mfma_f32_16x16x32_bf16(a[mi], b[ni], acc[mi][ni], 0, 0, 0);
  }

  // C/D layout (verified m89): col = lane&15, row = (lane>>4)*4 + reg
  const int rgrp = (lane >> 4) << 2;
  for (int ni = 0; ni < 2; ++ni) {
    const int col = n0 + ni * 16 + lrow;
    const float bz = bias[col];
    for (int mi = 0; mi < 2; ++mi)
      for (int r = 0; r < 4; ++r) {
        const int row = m0 + mi * 16 + rgrp + r;
        if (row < M) C[(size_t)row * N + col] = acc[mi][ni][r] + bz;
      }
  }
}

// In-place 2D RoPE on q,k patch rows of fp32 qkv[S][2304]; q rows (incl CLS)
// pre-scaled by 1/8. One block per position s; thread = (head, pair i in 0..31).
__global__ __launch_bounds__(384) void rope_scale_kernel(float* __restrict__ qkv,
                                                         const int* __restrict__ coords) {
  const int s = blockIdx.x;
  const int h = threadIdx.x >> 5;
  const int i = threadIdx.x & 31;
  float* qp = qkv + (size_t)s * kQKVN + h * kD + 2 * i;
  if (s == 0) {  // CLS: no rope, just q scaling
    qp[0] *= kScale;
    qp[1] *= kScale;
    return;
  }
  const float cx = (float)coords[(s - 1) * 2] * 1e-5f;
  const float cy = (float)coords[(s - 1) * 2 + 1] * 1e-5f;
  const int j = i & 15;
  const float invf = __powf(10000.0f, -(float)j * (1.0f / 16.0f));
  const float ang = (i < 16 ? cx : cy) * invf;
  float sn, cs;
  __sincosf(ang, &sn, &cs);
  float x0 = qp[0], x1 = qp[1];
  qp[0] = (x0 * cs - x1 * sn) * kScale;
  qp[1] = (x1 * cs + x0 * sn) * kScale;
  float* kp = qp + kE;  // k block at +768
  x0 = kp[0]; x1 = kp[1];
  kp[0] = x0 * cs - x1 * sn;
  kp[1] = x1 * cs + x0 * sn;
}

// CLS query attends to all 4097 keys. 1 block/head, 16 waves, lane = dim.
// Per-wave online softmax over strided keys, LDS flash-combine.
__global__ __launch_bounds__(1024) void cls_attn_kernel(const float* __restrict__ qkv,
                                                        float* __restrict__ attn) {
  const int h = blockIdx.x;
  const int lane = threadIdx.x & 63;
  const int wave = threadIdx.x >> 6;
  const float qd = qkv[h * kD + lane];  // scaled q, row 0
  float m = -INFINITY, lsum = 0.f, acc = 0.f;
  for (int s = wave; s < kS; s += 16) {
    const float* kr = qkv + (size_t)s * kQKVN + kE + h * kD;
    float t = qd * kr[lane];
    t += __shfl_xor(t, 1); t += __shfl_xor(t, 2); t += __shfl_xor(t, 4);
    t += __shfl_xor(t, 8); t += __shfl_xor(t, 16); t += __shfl_xor(t, 32);
    const float vd = qkv[(size_t)s * kQKVN + 2 * kE + h * kD + lane];
    const float mnew = fmaxf(m, t);
    const float cor = __expf(m - mnew);  // exp(-inf)=0 on first iter
    const float p = __expf(t - mnew);
    lsum = lsum * cor + p;
    acc = acc * cor + p * vd;
    m = mnew;
  }
  __shared__ float sm[16], sl[16], sa[16][64];
  sa[wave][lane] = acc;
  if (lane == 0) { sm[wave] = m; sl[wave] = lsum; }
  __syncthreads();
  if (wave == 0) {
    float M = -INFINITY;
    for (int w = 0; w < 16; ++w) M = fmaxf(M, sm[w]);
    float Lt = 0.f, Av = 0.f;
    for (int w = 0; w < 16; ++w) {
      const float c = __expf(sm[w] - M);
      Lt += sl[w] * c;
      Av += sa[w][lane] * c;
    }
    attn[h * kD + lane] = Av / Lt;
  }
}

// Patch attention: 1 wave per (head, position l); lane = dim.
// 34 keys: j=0 -> CLS (s=0); j=1..33 -> window l+(j-17)*4 (valid in [0,4096)).
__global__ __launch_bounds__(256) void patch_attn_kernel(const float* __restrict__ qkv,
                                                         float* __restrict__ attn) {
  const int lane = threadIdx.x & 63;
  const int gw = blockIdx.x * 4 + (threadIdx.x >> 6);
  const int h = gw >> 12;
  const int l = gw & 4095;
  const size_t s = l + 1;
  const float qd = qkv[s * kQKVN + h * kD + lane];
  float sc = -INFINITY;  // lane j holds score j (j<34)
#pragma unroll 1
  for (int j = 0; j < 34; ++j) {
    int ks;
    bool valid;
    if (j == 0) { ks = 0; valid = true; }
    else {
      const int kl = l + (j - 17) * kDil;
      valid = (kl >= 0) & (kl < kL);
      ks = kl + 1;
    }
    if (valid) {  // wave-uniform branch
      float t = qd * qkv[(size_t)ks * kQKVN + kE + h * kD + lane];
      t += __shfl_xor(t, 1); t += __shfl_xor(t, 2); t += __shfl_xor(t, 4);
      t += __shfl_xor(t, 8); t += __shfl_xor(t, 16); t += __shfl_xor(t, 32);
      if (lane == j) sc = t;
    }
  }
  float m = sc;
  m = fmaxf(m, __shfl_xor(m, 1)); m = fmaxf(m, __shfl_xor(m, 2));
  m = fmaxf(m, __shfl_xor(m, 4)); m = fmaxf(m, __shfl_xor(m, 8));
  m = fmaxf(m, __shfl_xor(m, 16)); m = fmaxf(m, __shfl_xor(m, 32));
  const float p = (sc == -INFINITY) ? 0.f : __expf(sc - m);
  float lsum = p;
  lsum += __shfl_xor(lsum, 1); lsum += __shfl_xor(lsum, 2); lsum += __shfl_xor(lsum, 4);
  lsum += __shfl_xor(lsum, 8); lsum += __shfl_xor(lsum, 16); lsum += __shfl_xor(lsum, 32);
  float acc = 0.f;
#pragma unroll 1
  for (int j = 0; j < 34; ++j) {
    const float pj = __shfl(p, j);  // uniform broadcast
    if (pj > 0.f) {
      const int ks2 = (j == 0) ? 0 : (l + (j - 17) * kDil + 1);
      acc += pj * qkv[(size_t)ks2 * kQKVN + 2 * kE + h * kD + lane];
    }
  }
  attn[s * (size_t)kE + h * kD + lane] = acc / lsum;
}

}  // namespace

extern "C" void kernel_launch(void* const* d_in, const int* in_sizes, int n_in,
                              void* d_out, int out_size, void* d_ws, size_t ws_size,
                              hipStream_t stream) {
  const float* x = (const float*)d_in[0];
  const int* coords = (const int*)d_in[1];
  const float* qkv_w = (const float*)d_in[2];
  const float* qkv_b = (const float*)d_in[3];
  const float* out_w = (const float*)d_in[4];
  const float* out_b = (const float*)d_in[5];
  float* out = (float*)d_out;

  float* qkv = (float*)d_ws;  // fp32 [4097][2304]
  float* attn = (float*)((char*)d_ws + (size_t)kS * kQKVN * sizeof(float));  // fp32 [4097][768]

  dim3 g1(129, 18);  // ceil(4097/32), 2304/128
  gemm_wt_kernel<<<g1, 256, 0, stream>>>(x, qkv_w, qkv_b, qkv, kS, kQKVN, kE);
  rope_scale_kernel<<<kS, 384, 0, stream>>>(qkv, coords);
  cls_attn_kernel<<<kH, 1024, 0, stream>>>(qkv, attn);
  patch_attn_kernel<<<kH * kL / 4, 256, 0, stream>>>(qkv, attn);
  dim3 g2(129, 6);  // ceil(4097/32), 768/128
  gemm_wt_kernel<<<g2, 256, 0, stream>>>(attn, out_w, out_b, out, kS, kE, kE);
}

// Round 3
// 403.860 us; speedup vs baseline: 1.5513x; 1.5513x over previous
//
#include <hip/hip_runtime.h>
#include <hip/hip_bf16.h>

namespace {

constexpr int kS = 4097;      // sequence incl. CLS
constexpr int kL = 4096;      // patch tokens
constexpr int kE = 768;
constexpr int kH = 12;
constexpr int kD = 64;
constexpr int kQKVN = 2304;
constexpr int kDil = 4;
constexpr float kScale = 0.125f;  // 1/sqrt(64)

typedef short short8 __attribute__((ext_vector_type(8)));
typedef short short4v __attribute__((ext_vector_type(4)));
typedef float f32x4 __attribute__((ext_vector_type(4)));

__device__ inline short f2bf(float x) {
  __hip_bfloat16 b = __float2bfloat16(x);
  return *reinterpret_cast<short*>(&b);
}

#define GLOAD_LDS16(g, l)                                                        \
  __builtin_amdgcn_global_load_lds(                                              \
      (const __attribute__((address_space(1))) unsigned int*)(g),                \
      (__attribute__((address_space(3))) unsigned int*)(l), 16, 0, 0)

// fp32 -> bf16 convert, x4 vectorized, grid-stride.
__global__ __launch_bounds__(256) void cvt_kernel(const float* __restrict__ in,
                                                  short* __restrict__ outp, int n4) {
  int i = blockIdx.x * blockDim.x + threadIdx.x;
  const int stride = gridDim.x * blockDim.x;
  for (; i < n4; i += stride) {
    f32x4 v = reinterpret_cast<const f32x4*>(in)[i];
    short4v o;
#pragma unroll
    for (int j = 0; j < 4; ++j) o[j] = f2bf(v[j]);
    reinterpret_cast<short4v*>(outp)[i] = o;
  }
}

// m97-structure GEMM: C[M][N](f32) = A(bf16)[clamped M][K] * W(bf16)[N][K]^T + bias(f32).
// 128x128 tile, BK=32, 4 waves (2x2), 4x4 16x16x32 fragments per wave,
// single-buffer LDS, global_load_lds width=16 staging. N%128==0, K%32==0.
__global__ __launch_bounds__(256) void gemm_tile_kernel(const short* __restrict__ A,
                                                        const short* __restrict__ W,
                                                        const float* __restrict__ bias,
                                                        float* __restrict__ C,
                                                        int Mreal, int N, int K) {
  __shared__ short Ash[128 * 32];
  __shared__ short Bsh[128 * 32];
  const int t = threadIdx.x;
  const int lane = t & 63;
  const int wave = t >> 6;
  const int wr = wave >> 1, wc = wave & 1;
  const int m0 = blockIdx.x * 128;
  const int n0 = blockIdx.y * 128;
  const int lrow = lane & 15;
  const int kg = (lane >> 4) << 3;  // fragment K offset (elems)

  // Staging map: thread t stages 16B = row (t>>2), cols (t&3)*8 of a 64-row half-tile.
  const int srow = t >> 2;
  const int scol = (t & 3) << 3;
  int arow0 = m0 + srow;       if (arow0 > Mreal - 1) arow0 = Mreal - 1;
  int arow1 = m0 + 64 + srow;  if (arow1 > Mreal - 1) arow1 = Mreal - 1;
  const int brow0 = n0 + srow;
  const int brow1 = n0 + 64 + srow;

  f32x4 acc[4][4] = {};

  for (int k0 = 0; k0 < K; k0 += 32) {
    __syncthreads();  // previous compute done before overwrite
    GLOAD_LDS16(A + (size_t)arow0 * K + k0 + scol, Ash + t * 8);
    GLOAD_LDS16(A + (size_t)arow1 * K + k0 + scol, Ash + 2048 + t * 8);
    GLOAD_LDS16(W + (size_t)brow0 * K + k0 + scol, Bsh + t * 8);
    GLOAD_LDS16(W + (size_t)brow1 * K + k0 + scol, Bsh + 2048 + t * 8);
    __syncthreads();  // compiler drains vmcnt(0) before barrier

    short8 a[4], b[4];
#pragma unroll
    for (int mi = 0; mi < 4; ++mi)
      a[mi] = *reinterpret_cast<const short8*>(Ash + (wr * 64 + mi * 16 + lrow) * 32 + kg);
#pragma unroll
    for (int ni = 0; ni < 4; ++ni)
      b[ni] = *reinterpret_cast<const short8*>(Bsh + (wc * 64 + ni * 16 + lrow) * 32 + kg);
#pragma unroll
    for (int mi = 0; mi < 4; ++mi)
#pragma unroll
      for (int ni = 0; ni < 4; ++ni)
        acc[mi][ni] = __builtin_amdgcn_mfma_f32_16x16x32_bf16(a[mi], b[ni], acc[mi][ni], 0, 0, 0);
  }

  // C/D layout (m89): col = lane&15 (W row), row = (lane>>4)*4 + reg (A row)
  const int rg = (lane >> 4) << 2;
  for (int ni = 0; ni < 4; ++ni) {
    const int col = n0 + wc * 64 + ni * 16 + lrow;
    const float bz = bias[col];
    for (int mi = 0; mi < 4; ++mi) {
      const int rowb = m0 + wr * 64 + mi * 16 + rg;
#pragma unroll
      for (int r = 0; r < 4; ++r) {
        const int row = rowb + r;
        if (row < Mreal) C[(size_t)row * N + col] = acc[mi][ni][r] + bz;
      }
    }
  }
}

// In-place 2D RoPE on q,k patch rows of fp32 qkv[S][2304]; q rows (incl CLS)
// pre-scaled by 1/8. One block per position s; thread = (head, pair i in 0..31).
__global__ __launch_bounds__(384) void rope_scale_kernel(float* __restrict__ qkv,
                                                         const int* __restrict__ coords) {
  const int s = blockIdx.x;
  const int h = threadIdx.x >> 5;
  const int i = threadIdx.x & 31;
  float* qp = qkv + (size_t)s * kQKVN + h * kD + 2 * i;
  if (s == 0) {  // CLS: no rope, just q scaling
    qp[0] *= kScale;
    qp[1] *= kScale;
    return;
  }
  const float cx = (float)coords[(s - 1) * 2] * 1e-5f;
  const float cy = (float)coords[(s - 1) * 2 + 1] * 1e-5f;
  const int j = i & 15;
  const float invf = __powf(10000.0f, -(float)j * (1.0f / 16.0f));
  const float ang = (i < 16 ? cx : cy) * invf;
  float sn, cs;
  __sincosf(ang, &sn, &cs);
  float x0 = qp[0], x1 = qp[1];
  qp[0] = (x0 * cs - x1 * sn) * kScale;
  qp[1] = (x1 * cs + x0 * sn) * kScale;
  float* kp = qp + kE;  // k block at +768
  x0 = kp[0]; x1 = kp[1];
  kp[0] = x0 * cs - x1 * sn;
  kp[1] = x1 * cs + x0 * sn;
}

// CLS query attends to all 4097 keys. 1 block/head, 16 waves, lane = dim.
__global__ __launch_bounds__(1024) void cls_attn_kernel(const float* __restrict__ qkv,
                                                        short* __restrict__ attn) {
  const int h = blockIdx.x;
  const int lane = threadIdx.x & 63;
  const int wave = threadIdx.x >> 6;
  const float qd = qkv[h * kD + lane];  // scaled q, row 0
  float m = -INFINITY, lsum = 0.f, acc = 0.f;
  for (int s = wave; s < kS; s += 16) {
    const float* kr = qkv + (size_t)s * kQKVN + kE + h * kD;
    float t = qd * kr[lane];
    t += __shfl_xor(t, 1); t += __shfl_xor(t, 2); t += __shfl_xor(t, 4);
    t += __shfl_xor(t, 8); t += __shfl_xor(t, 16); t += __shfl_xor(t, 32);
    const float vd = qkv[(size_t)s * kQKVN + 2 * kE + h * kD + lane];
    const float mnew = fmaxf(m, t);
    const float cor = __expf(m - mnew);  // exp(-inf)=0 on first iter
    const float p = __expf(t - mnew);
    lsum = lsum * cor + p;
    acc = acc * cor + p * vd;
    m = mnew;
  }
  __shared__ float sm[16], sl[16], sa[16][64];
  sa[wave][lane] = acc;
  if (lane == 0) { sm[wave] = m; sl[wave] = lsum; }
  __syncthreads();
  if (wave == 0) {
    float M = -INFINITY;
    for (int w = 0; w < 16; ++w) M = fmaxf(M, sm[w]);
    float Lt = 0.f, Av = 0.f;
    for (int w = 0; w < 16; ++w) {
      const float c = __expf(sm[w] - M);
      Lt += sl[w] * c;
      Av += sa[w][lane] * c;
    }
    attn[h * kD + lane] = f2bf(Av / Lt);
  }
}

// Patch attention: 1 wave per (head, position l); lane = dim.
// 34 keys: j=0 -> CLS (s=0); j=1..33 -> window l+(j-17)*4 (valid in [0,4096)).
__global__ __launch_bounds__(256) void patch_attn_kernel(const float* __restrict__ qkv,
                                                         short* __restrict__ attn) {
  const int lane = threadIdx.x & 63;
  const int gw = blockIdx.x * 4 + (threadIdx.x >> 6);
  const int h = gw >> 12;
  const int l = gw & 4095;
  const size_t s = l + 1;
  const float qd = qkv[s * kQKVN + h * kD + lane];
  float sc = -INFINITY;  // lane j holds score j (j<34)
#pragma unroll 1
  for (int j = 0; j < 34; ++j) {
    int ks;
    bool valid;
    if (j == 0) { ks = 0; valid = true; }
    else {
      const int kl = l + (j - 17) * kDil;
      valid = (kl >= 0) & (kl < kL);
      ks = kl + 1;
    }
    if (valid) {  // wave-uniform branch
      float t = qd * qkv[(size_t)ks * kQKVN + kE + h * kD + lane];
      t += __shfl_xor(t, 1); t += __shfl_xor(t, 2); t += __shfl_xor(t, 4);
      t += __shfl_xor(t, 8); t += __shfl_xor(t, 16); t += __shfl_xor(t, 32);
      if (lane == j) sc = t;
    }
  }
  float m = sc;
  m = fmaxf(m, __shfl_xor(m, 1)); m = fmaxf(m, __shfl_xor(m, 2));
  m = fmaxf(m, __shfl_xor(m, 4)); m = fmaxf(m, __shfl_xor(m, 8));
  m = fmaxf(m, __shfl_xor(m, 16)); m = fmaxf(m, __shfl_xor(m, 32));
  const float p = (sc == -INFINITY) ? 0.f : __expf(sc - m);
  float lsum = p;
  lsum += __shfl_xor(lsum, 1); lsum += __shfl_xor(lsum, 2); lsum += __shfl_xor(lsum, 4);
  lsum += __shfl_xor(lsum, 8); lsum += __shfl_xor(lsum, 16); lsum += __shfl_xor(lsum, 32);
  float acc = 0.f;
#pragma unroll 1
  for (int j = 0; j < 34; ++j) {
    const float pj = __shfl(p, j);  // uniform broadcast
    if (pj > 0.f) {
      const int ks2 = (j == 0) ? 0 : (l + (j - 17) * kDil + 1);
      acc += pj * qkv[(size_t)ks2 * kQKVN + 2 * kE + h * kD + lane];
    }
  }
  attn[s * (size_t)kE + h * kD + lane] = f2bf(acc / lsum);
}

}  // namespace

extern "C" void kernel_launch(void* const* d_in, const int* in_sizes, int n_in,
                              void* d_out, int out_size, void* d_ws, size_t ws_size,
                              hipStream_t stream) {
  const float* x = (const float*)d_in[0];
  const int* coords = (const int*)d_in[1];
  const float* qkv_w = (const float*)d_in[2];
  const float* qkv_b = (const float*)d_in[3];
  const float* out_w = (const float*)d_in[4];
  const float* out_b = (const float*)d_in[5];
  float* out = (float*)d_out;

  // Workspace layout (256B-aligned segments):
  char* p = (char*)d_ws;
  float* qkv = (float*)p;                 p += (size_t)kS * kQKVN * sizeof(float);   // 37.8 MB
  short* xb = (short*)p;                  p += (size_t)kS * kE * sizeof(short);      // 6.3 MB
  short* wb = (short*)p;                  p += (size_t)kQKVN * kE * sizeof(short);   // 3.5 MB
  short* owb = (short*)p;                 p += (size_t)kE * kE * sizeof(short);      // 1.2 MB
  short* attnb = (short*)p;                                                          // 6.3 MB

  const int n4x = kS * kE / 4;
  const int n4w = kQKVN * kE / 4;
  const int n4o = kE * kE / 4;
  cvt_kernel<<<2048, 256, 0, stream>>>(x, xb, n4x);
  cvt_kernel<<<2048, 256, 0, stream>>>(qkv_w, wb, n4w);
  cvt_kernel<<<1024, 256, 0, stream>>>(out_w, owb, n4o);

  dim3 g1(33, 18);  // ceil(4097/128), 2304/128
  gemm_tile_kernel<<<g1, 256, 0, stream>>>(xb, wb, qkv_b, qkv, kS, kQKVN, kE);
  rope_scale_kernel<<<kS, 384, 0, stream>>>(qkv, coords);
  cls_attn_kernel<<<kH, 1024, 0, stream>>>(qkv, attnb);
  patch_attn_kernel<<<kH * kL / 4, 256, 0, stream>>>(qkv, attnb);
  dim3 g2(33, 6);  // ceil(4097/128), 768/128
  gemm_tile_kernel<<<g2, 256, 0, stream>>>(attnb, owb, out_b, out, kS, kE, kE);
}

// Round 4
// 236.971 us; speedup vs baseline: 2.6438x; 1.7043x over previous
//
#include <hip/hip_runtime.h>
#include <hip/hip_bf16.h>

namespace {

constexpr int kS = 4097;      // sequence incl. CLS
constexpr int kL = 4096;      // patch tokens
constexpr int kE = 768;
constexpr int kH = 12;
constexpr int kD = 64;
constexpr int kQKVN = 2304;
constexpr int kT = 1024;      // lattice length per residue (kL / kDil)
constexpr float kScale = 0.125f;  // 1/sqrt(64)

typedef short short8 __attribute__((ext_vector_type(8)));
typedef short short4v __attribute__((ext_vector_type(4)));
typedef float f32x4 __attribute__((ext_vector_type(4)));

__device__ inline short f2bf(float x) {
  __hip_bfloat16 b = __float2bfloat16(x);
  return *reinterpret_cast<short*>(&b);
}

#define GLOAD_LDS16(g, l)                                                        \
  __builtin_amdgcn_global_load_lds(                                              \
      (const __attribute__((address_space(1))) unsigned int*)(g),                \
      (__attribute__((address_space(3))) unsigned int*)(l), 16, 0, 0)

// Load 8 consecutive fp32, convert to a bf16x8 MFMA fragment.
__device__ inline short8 load_frag8(const float* __restrict__ p) {
  f32x4 lo = *reinterpret_cast<const f32x4*>(p);
  f32x4 hi = *reinterpret_cast<const f32x4*>(p + 4);
  short8 r;
#pragma unroll
  for (int j = 0; j < 4; ++j) {
    r[j] = f2bf(lo[j]);
    r[j + 4] = f2bf(hi[j]);
  }
  return r;
}

// fp32 -> bf16 convert, x4 vectorized, grid-stride.
__global__ __launch_bounds__(256) void cvt_kernel(const float* __restrict__ in,
                                                  short* __restrict__ outp, int n4) {
  int i = blockIdx.x * blockDim.x + threadIdx.x;
  const int stride = gridDim.x * blockDim.x;
  for (; i < n4; i += stride) {
    f32x4 v = reinterpret_cast<const f32x4*>(in)[i];
    short4v o;
#pragma unroll
    for (int j = 0; j < 4; ++j) o[j] = f2bf(v[j]);
    reinterpret_cast<short4v*>(outp)[i] = o;
  }
}

// m97-structure GEMM: C[M][N](f32) = A(bf16)[M][K] * W(bf16)[N][K]^T + bias(f32).
__global__ __launch_bounds__(256) void gemm_tile_kernel(const short* __restrict__ A,
                                                        const short* __restrict__ W,
                                                        const float* __restrict__ bias,
                                                        float* __restrict__ C,
                                                        int Mreal, int N, int K) {
  __shared__ short Ash[128 * 32];
  __shared__ short Bsh[128 * 32];
  const int t = threadIdx.x;
  const int lane = t & 63;
  const int wave = t >> 6;
  const int wr = wave >> 1, wc = wave & 1;
  const int m0 = blockIdx.x * 128;
  const int n0 = blockIdx.y * 128;
  const int lrow = lane & 15;
  const int kg = (lane >> 4) << 3;

  const int srow = t >> 2;
  const int scol = (t & 3) << 3;
  int arow0 = m0 + srow;       if (arow0 > Mreal - 1) arow0 = Mreal - 1;
  int arow1 = m0 + 64 + srow;  if (arow1 > Mreal - 1) arow1 = Mreal - 1;
  const int brow0 = n0 + srow;
  const int brow1 = n0 + 64 + srow;

  f32x4 acc[4][4] = {};

  for (int k0 = 0; k0 < K; k0 += 32) {
    __syncthreads();
    GLOAD_LDS16(A + (size_t)arow0 * K + k0 + scol, Ash + t * 8);
    GLOAD_LDS16(A + (size_t)arow1 * K + k0 + scol, Ash + 2048 + t * 8);
    GLOAD_LDS16(W + (size_t)brow0 * K + k0 + scol, Bsh + t * 8);
    GLOAD_LDS16(W + (size_t)brow1 * K + k0 + scol, Bsh + 2048 + t * 8);
    __syncthreads();

    short8 a[4], b[4];
#pragma unroll
    for (int mi = 0; mi < 4; ++mi)
      a[mi] = *reinterpret_cast<const short8*>(Ash + (wr * 64 + mi * 16 + lrow) * 32 + kg);
#pragma unroll
    for (int ni = 0; ni < 4; ++ni)
      b[ni] = *reinterpret_cast<const short8*>(Bsh + (wc * 64 + ni * 16 + lrow) * 32 + kg);
#pragma unroll
    for (int mi = 0; mi < 4; ++mi)
#pragma unroll
      for (int ni = 0; ni < 4; ++ni)
        acc[mi][ni] = __builtin_amdgcn_mfma_f32_16x16x32_bf16(a[mi], b[ni], acc[mi][ni], 0, 0, 0);
  }

  const int rg = (lane >> 4) << 2;
  for (int ni = 0; ni < 4; ++ni) {
    const int col = n0 + wc * 64 + ni * 16 + lrow;
    const float bz = bias[col];
    for (int mi = 0; mi < 4; ++mi) {
      const int rowb = m0 + wr * 64 + mi * 16 + rg;
#pragma unroll
      for (int r = 0; r < 4; ++r) {
        const int row = rowb + r;
        if (row < Mreal) C[(size_t)row * N + col] = acc[mi][ni][r] + bz;
      }
    }
  }
}

// In-place 2D RoPE on q,k patch rows of fp32 qkv[S][2304]; q rows (incl CLS)
// pre-scaled by 1/8.
__global__ __launch_bounds__(384) void rope_scale_kernel(float* __restrict__ qkv,
                                                         const int* __restrict__ coords) {
  const int s = blockIdx.x;
  const int h = threadIdx.x >> 5;
  const int i = threadIdx.x & 31;
  float* qp = qkv + (size_t)s * kQKVN + h * kD + 2 * i;
  if (s == 0) {
    qp[0] *= kScale;
    qp[1] *= kScale;
    return;
  }
  const float cx = (float)coords[(s - 1) * 2] * 1e-5f;
  const float cy = (float)coords[(s - 1) * 2 + 1] * 1e-5f;
  const int j = i & 15;
  const float invf = __powf(10000.0f, -(float)j * (1.0f / 16.0f));
  const float ang = (i < 16 ? cx : cy) * invf;
  float sn, cs;
  __sincosf(ang, &sn, &cs);
  float x0 = qp[0], x1 = qp[1];
  qp[0] = (x0 * cs - x1 * sn) * kScale;
  qp[1] = (x1 * cs + x0 * sn) * kScale;
  float* kp = qp + kE;
  x0 = kp[0]; x1 = kp[1];
  kp[0] = x0 * cs - x1 * sn;
  kp[1] = x1 * cs + x0 * sn;
}

// CLS query attends to all 4097 keys. 1 block/head, 16 waves, lane = dim.
__global__ __launch_bounds__(1024) void cls_attn_kernel(const float* __restrict__ qkv,
                                                        short* __restrict__ attn) {
  const int h = blockIdx.x;
  const int lane = threadIdx.x & 63;
  const int wave = threadIdx.x >> 6;
  const float qd = qkv[h * kD + lane];
  float m = -INFINITY, lsum = 0.f, acc = 0.f;
  for (int s = wave; s < kS; s += 16) {
    const float* kr = qkv + (size_t)s * kQKVN + kE + h * kD;
    float t = qd * kr[lane];
    t += __shfl_xor(t, 1); t += __shfl_xor(t, 2); t += __shfl_xor(t, 4);
    t += __shfl_xor(t, 8); t += __shfl_xor(t, 16); t += __shfl_xor(t, 32);
    const float vd = qkv[(size_t)s * kQKVN + 2 * kE + h * kD + lane];
    const float mnew = fmaxf(m, t);
    const float cor = __expf(m - mnew);
    const float p = __expf(t - mnew);
    lsum = lsum * cor + p;
    acc = acc * cor + p * vd;
    m = mnew;
  }
  __shared__ float sm[16], sl[16], sa[16][64];
  sa[wave][lane] = acc;
  if (lane == 0) { sm[wave] = m; sl[wave] = lsum; }
  __syncthreads();
  if (wave == 0) {
    float M = -INFINITY;
    for (int w = 0; w < 16; ++w) M = fmaxf(M, sm[w]);
    float Lt = 0.f, Av = 0.f;
    for (int w = 0; w < 16; ++w) {
      const float c = __expf(sm[w] - M);
      Lt += sl[w] * c;
      Av += sa[w][lane] * c;
    }
    attn[h * kD + lane] = f2bf(Av / Lt);
  }
}

// MFMA patch attention in lattice coordinates.
// l = 4t + res; query (h,res,t) attends lattice keys u in [t-16,t+16] + CLS.
// 1 wave per (h, res, 32-query tile): 12*4*32 = 1536 waves, 4 waves/block.
// QK^T: S[32][64] (+CLS col) via 16x16x32 bf16 MFMA, operands gathered from
// fp32 qkv. Softmax in C-layout (4-step shfl over 16-lane group), P normalized
// pre-PV, staged in wave-private LDS [32][104] bf16 (pad -> conflict-free).
// PV transposed: out[d][q] = sum_kk V^T[d][kk] P[q][kk], V^T gathered direct.
__global__ __launch_bounds__(256) void patch_attn_mfma_kernel(const float* __restrict__ qkv,
                                                              short* __restrict__ attn) {
  __shared__ short Pl[4][32][104];
  const int lane = threadIdx.x & 63;
  const int wv = threadIdx.x >> 6;
  const int unit = blockIdx.x * 4 + wv;
  const int t0 = (unit & 31) * 32;
  const int res = (unit >> 5) & 3;
  const int h = unit >> 7;
  const int lrow = lane & 15;
  const int lgrp = lane >> 4;   // 0..3
  const int kg = lgrp * 8;      // K-element offset within a 32-wide k-step
  const int rg = lgrp * 4;      // C-layout row group

  // ---- QK^T ----
  f32x4 s_acc[2][4] = {};
  f32x4 s_cls[2] = {};
  short8 aq[2][2];
#pragma unroll
  for (int mi = 0; mi < 2; ++mi) {
    const int tq = t0 + mi * 16 + lrow;
    const size_t row = (size_t)(4 * tq + res + 1) * kQKVN + h * kD;
#pragma unroll
    for (int ks = 0; ks < 2; ++ks)
      aq[mi][ks] = load_frag8(qkv + row + ks * 32 + kg);
  }
#pragma unroll
  for (int ni = 0; ni < 4; ++ni) {
    int u = t0 - 16 + ni * 16 + lrow;
    u = min(max(u, 0), kT - 1);  // clamp; invalid cols masked in softmax
    const size_t row = (size_t)(4 * u + res + 1) * kQKVN + kE + h * kD;
    short8 bk[2];
#pragma unroll
    for (int ks = 0; ks < 2; ++ks) bk[ks] = load_frag8(qkv + row + ks * 32 + kg);
#pragma unroll
    for (int mi = 0; mi < 2; ++mi)
#pragma unroll
      for (int ks = 0; ks < 2; ++ks)
        s_acc[mi][ni] = __builtin_amdgcn_mfma_f32_16x16x32_bf16(aq[mi][ks], bk[ks], s_acc[mi][ni], 0, 0, 0);
  }
  {  // CLS key column: B-frag row 0 = k_cls, other rows zero (masked later)
    short8 bc[2] = {};
    if (lrow == 0) {
#pragma unroll
      for (int ks = 0; ks < 2; ++ks) bc[ks] = load_frag8(qkv + kE + h * kD + ks * 32 + kg);
    }
#pragma unroll
    for (int mi = 0; mi < 2; ++mi)
#pragma unroll
      for (int ks = 0; ks < 2; ++ks)
        s_cls[mi] = __builtin_amdgcn_mfma_f32_16x16x32_bf16(aq[mi][ks], bc[ks], s_cls[mi], 0, 0, 0);
  }

  // ---- zero-fill P cols 64..95 (CLS lands at col 64) ----
#pragma unroll
  for (int i = 0; i < 2; ++i) {
    const int idx = i * 64 + lane;  // covers 32 rows x 4 16B-chunks
    const int q = idx >> 2, ch = idx & 3;
    short8 z = {};
    *reinterpret_cast<short8*>(&Pl[wv][q][64 + ch * 8]) = z;
  }

  // ---- softmax per query row (C-layout), write normalized P ----
#pragma unroll
  for (int mi = 0; mi < 2; ++mi) {
#pragma unroll
    for (int r = 0; r < 4; ++r) {
      const int q = mi * 16 + rg + r;  // query offset in tile (0..31)
      float sw[4];
      float m = -INFINITY;
#pragma unroll
      for (int ni = 0; ni < 4; ++ni) {
        const int kk = ni * 16 + lrow;
        const int u = t0 - 16 + kk;
        const bool valid = (kk >= q) & (kk <= q + 32) & (u >= 0) & (u < kT);
        sw[ni] = valid ? s_acc[mi][ni][r] : -INFINITY;
        m = fmaxf(m, sw[ni]);
      }
      float scl = (lrow == 0) ? s_cls[mi][r] : -INFINITY;
      m = fmaxf(m, scl);
      m = fmaxf(m, __shfl_xor(m, 1)); m = fmaxf(m, __shfl_xor(m, 2));
      m = fmaxf(m, __shfl_xor(m, 4)); m = fmaxf(m, __shfl_xor(m, 8));
      float lsum = 0.f, ps[4];
#pragma unroll
      for (int ni = 0; ni < 4; ++ni) { ps[ni] = __expf(sw[ni] - m); lsum += ps[ni]; }
      const float pc = __expf(scl - m);
      lsum += pc;
      lsum += __shfl_xor(lsum, 1); lsum += __shfl_xor(lsum, 2);
      lsum += __shfl_xor(lsum, 4); lsum += __shfl_xor(lsum, 8);
      const float inv = __builtin_amdgcn_rcpf(lsum);
#pragma unroll
      for (int ni = 0; ni < 4; ++ni) Pl[wv][q][ni * 16 + lrow] = f2bf(ps[ni] * inv);
      if (lrow == 0) Pl[wv][q][64] = f2bf(pc * inv);
    }
  }

  // ---- PV: out[d][q] += V^T[d][kk] * P[q][kk] ----
  f32x4 o_acc[4][2] = {};
#pragma unroll
  for (int ks = 0; ks < 3; ++ks) {
    short8 bp[2];
#pragma unroll
    for (int nq = 0; nq < 2; ++nq)
      bp[nq] = *reinterpret_cast<const short8*>(&Pl[wv][nq * 16 + lrow][ks * 32 + kg]);
    short8 av[4];
#pragma unroll
    for (int md = 0; md < 4; ++md) {
      if (ks < 2) {
        const int d = md * 16 + lrow;
#pragma unroll
        for (int e = 0; e < 8; ++e) {
          const int kk = ks * 32 + kg + e;
          int u = t0 - 16 + kk;
          u = min(max(u, 0), kT - 1);  // invalid kk have P==0
          av[md][e] = f2bf(qkv[(size_t)(4 * u + res + 1) * kQKVN + 2 * kE + h * kD + d]);
        }
      } else {
        short8 z = {};
        av[md] = z;
        if (lgrp == 0)  // kk==64 -> v_cls
          av[md][0] = f2bf(qkv[2 * kE + h * kD + md * 16 + lrow]);
      }
#pragma unroll
      for (int nq = 0; nq < 2; ++nq)
        o_acc[md][nq] = __builtin_amdgcn_mfma_f32_16x16x32_bf16(av[md], bp[nq], o_acc[md][nq], 0, 0, 0);
    }
  }

  // ---- store: C col = q (lane&15), row = d (rg + r) ----
#pragma unroll
  for (int md = 0; md < 4; ++md)
#pragma unroll
    for (int nq = 0; nq < 2; ++nq)
#pragma unroll
      for (int r = 0; r < 4; ++r) {
        const int d = md * 16 + rg + r;
        const int q = nq * 16 + lrow;
        const int s = 4 * (t0 + q) + res + 1;
        attn[(size_t)s * kE + h * kD + d] = f2bf(o_acc[md][nq][r]);
      }
}

}  // namespace

extern "C" void kernel_launch(void* const* d_in, const int* in_sizes, int n_in,
                              void* d_out, int out_size, void* d_ws, size_t ws_size,
                              hipStream_t stream) {
  const float* x = (const float*)d_in[0];
  const int* coords = (const int*)d_in[1];
  const float* qkv_w = (const float*)d_in[2];
  const float* qkv_b = (const float*)d_in[3];
  const float* out_w = (const float*)d_in[4];
  const float* out_b = (const float*)d_in[5];
  float* out = (float*)d_out;

  char* p = (char*)d_ws;
  float* qkv = (float*)p;                 p += (size_t)kS * kQKVN * sizeof(float);
  short* xb = (short*)p;                  p += (size_t)kS * kE * sizeof(short);
  short* wb = (short*)p;                  p += (size_t)kQKVN * kE * sizeof(short);
  short* owb = (short*)p;                 p += (size_t)kE * kE * sizeof(short);
  short* attnb = (short*)p;

  const int n4x = kS * kE / 4;
  const int n4w = kQKVN * kE / 4;
  const int n4o = kE * kE / 4;
  cvt_kernel<<<2048, 256, 0, stream>>>(x, xb, n4x);
  cvt_kernel<<<2048, 256, 0, stream>>>(qkv_w, wb, n4w);
  cvt_kernel<<<1024, 256, 0, stream>>>(out_w, owb, n4o);

  dim3 g1(33, 18);
  gemm_tile_kernel<<<g1, 256, 0, stream>>>(xb, wb, qkv_b, qkv, kS, kQKVN, kE);
  rope_scale_kernel<<<kS, 384, 0, stream>>>(qkv, coords);
  cls_attn_kernel<<<kH, 1024, 0, stream>>>(qkv, attnb);
  patch_attn_mfma_kernel<<<384, 256, 0, stream>>>(qkv, attnb);
  dim3 g2(33, 6);
  gemm_tile_kernel<<<g2, 256, 0, stream>>>(attnb, owb, out_b, out, kS, kE, kE);
}

// Round 5
// 127.327 us; speedup vs baseline: 4.9204x; 1.8611x over previous
//
#include <hip/hip_runtime.h>
#include <hip/hip_bf16.h>

namespace {

constexpr int kS = 4097;      // sequence incl. CLS
constexpr int kL = 4096;      // patch tokens
constexpr int kE = 768;
constexpr int kH = 12;
constexpr int kD = 64;
constexpr int kQKVN = 2304;
constexpr int kT = 1024;      // lattice length per residue (kL / kDil)
constexpr int kClsChunks = 32;
constexpr int kClsStride = 68;    // 64 acc + m + l, padded
constexpr float kScale = 0.125f;  // 1/sqrt(64)

typedef short short8 __attribute__((ext_vector_type(8)));
typedef short short4v __attribute__((ext_vector_type(4)));
typedef float f32x4 __attribute__((ext_vector_type(4)));

__device__ inline short f2bf(float x) {
  __hip_bfloat16 b = __float2bfloat16(x);
  return *reinterpret_cast<short*>(&b);
}

#define GLOAD_LDS16(g, l)                                                        \
  __builtin_amdgcn_global_load_lds(                                              \
      (const __attribute__((address_space(1))) unsigned int*)(g),                \
      (__attribute__((address_space(3))) unsigned int*)(l), 16, 0, 0)

// Load 8 consecutive fp32, convert to a bf16x8 MFMA fragment.
__device__ inline short8 load_frag8(const float* __restrict__ p) {
  f32x4 lo = *reinterpret_cast<const f32x4*>(p);
  f32x4 hi = *reinterpret_cast<const f32x4*>(p + 4);
  short8 r;
#pragma unroll
  for (int j = 0; j < 4; ++j) {
    r[j] = f2bf(lo[j]);
    r[j + 4] = f2bf(hi[j]);
  }
  return r;
}

// fp32 -> bf16 convert, x4 vectorized, grid-stride.
__global__ __launch_bounds__(256) void cvt_kernel(const float* __restrict__ in,
                                                  short* __restrict__ outp, int n4) {
  int i = blockIdx.x * blockDim.x + threadIdx.x;
  const int stride = gridDim.x * blockDim.x;
  for (; i < n4; i += stride) {
    f32x4 v = reinterpret_cast<const f32x4*>(in)[i];
    short4v o;
#pragma unroll
    for (int j = 0; j < 4; ++j) o[j] = f2bf(v[j]);
    reinterpret_cast<short4v*>(outp)[i] = o;
  }
}

// m97-structure GEMM: C[M][N](f32) = A(bf16)[M][K] * W(bf16)[N][K]^T + bias(f32).
__global__ __launch_bounds__(256) void gemm_tile_kernel(const short* __restrict__ A,
                                                        const short* __restrict__ W,
                                                        const float* __restrict__ bias,
                                                        float* __restrict__ C,
                                                        int Mreal, int N, int K) {
  __shared__ short Ash[128 * 32];
  __shared__ short Bsh[128 * 32];
  const int t = threadIdx.x;
  const int lane = t & 63;
  const int wave = t >> 6;
  const int wr = wave >> 1, wc = wave & 1;
  const int m0 = blockIdx.x * 128;
  const int n0 = blockIdx.y * 128;
  const int lrow = lane & 15;
  const int kg = (lane >> 4) << 3;

  const int srow = t >> 2;
  const int scol = (t & 3) << 3;
  int arow0 = m0 + srow;       if (arow0 > Mreal - 1) arow0 = Mreal - 1;
  int arow1 = m0 + 64 + srow;  if (arow1 > Mreal - 1) arow1 = Mreal - 1;
  const int brow0 = n0 + srow;
  const int brow1 = n0 + 64 + srow;

  f32x4 acc[4][4] = {};

  for (int k0 = 0; k0 < K; k0 += 32) {
    __syncthreads();
    GLOAD_LDS16(A + (size_t)arow0 * K + k0 + scol, Ash + t * 8);
    GLOAD_LDS16(A + (size_t)arow1 * K + k0 + scol, Ash + 2048 + t * 8);
    GLOAD_LDS16(W + (size_t)brow0 * K + k0 + scol, Bsh + t * 8);
    GLOAD_LDS16(W + (size_t)brow1 * K + k0 + scol, Bsh + 2048 + t * 8);
    __syncthreads();

    short8 a[4], b[4];
#pragma unroll
    for (int mi = 0; mi < 4; ++mi)
      a[mi] = *reinterpret_cast<const short8*>(Ash + (wr * 64 + mi * 16 + lrow) * 32 + kg);
#pragma unroll
    for (int ni = 0; ni < 4; ++ni)
      b[ni] = *reinterpret_cast<const short8*>(Bsh + (wc * 64 + ni * 16 + lrow) * 32 + kg);
#pragma unroll
    for (int mi = 0; mi < 4; ++mi)
#pragma unroll
      for (int ni = 0; ni < 4; ++ni)
        acc[mi][ni] = __builtin_amdgcn_mfma_f32_16x16x32_bf16(a[mi], b[ni], acc[mi][ni], 0, 0, 0);
  }

  const int rg = (lane >> 4) << 2;
  for (int ni = 0; ni < 4; ++ni) {
    const int col = n0 + wc * 64 + ni * 16 + lrow;
    const float bz = bias[col];
    for (int mi = 0; mi < 4; ++mi) {
      const int rowb = m0 + wr * 64 + mi * 16 + rg;
#pragma unroll
      for (int r = 0; r < 4; ++r) {
        const int row = rowb + r;
        if (row < Mreal) C[(size_t)row * N + col] = acc[mi][ni][r] + bz;
      }
    }
  }
}

// In-place 2D RoPE on q,k patch rows of fp32 qkv[S][2304]; q rows (incl CLS)
// pre-scaled by 1/8.
__global__ __launch_bounds__(384) void rope_scale_kernel(float* __restrict__ qkv,
                                                         const int* __restrict__ coords) {
  const int s = blockIdx.x;
  const int h = threadIdx.x >> 5;
  const int i = threadIdx.x & 31;
  float* qp = qkv + (size_t)s * kQKVN + h * kD + 2 * i;
  if (s == 0) {
    qp[0] *= kScale;
    qp[1] *= kScale;
    return;
  }
  const float cx = (float)coords[(s - 1) * 2] * 1e-5f;
  const float cy = (float)coords[(s - 1) * 2 + 1] * 1e-5f;
  const int j = i & 15;
  const float invf = __powf(10000.0f, -(float)j * (1.0f / 16.0f));
  const float ang = (i < 16 ? cx : cy) * invf;
  float sn, cs;
  __sincosf(ang, &sn, &cs);
  float x0 = qp[0], x1 = qp[1];
  qp[0] = (x0 * cs - x1 * sn) * kScale;
  qp[1] = (x1 * cs + x0 * sn) * kScale;
  float* kp = qp + kE;
  x0 = kp[0]; x1 = kp[1];
  kp[0] = x0 * cs - x1 * sn;
  kp[1] = x1 * cs + x0 * sn;
}

// CLS attention, split-K pass 1: block (h, c) handles 128 keys (last chunk 129).
// 4 waves, lane = dim; per-wave online softmax; LDS combine; partial out.
__global__ __launch_bounds__(256) void cls_partial_kernel(const float* __restrict__ qkv,
                                                          float* __restrict__ part) {
  const int h = blockIdx.x;
  const int c = blockIdx.y;
  const int lane = threadIdx.x & 63;
  const int wave = threadIdx.x >> 6;
  const int start = c * 128;
  const int end = (c == kClsChunks - 1) ? kS : start + 128;
  const float qd = qkv[h * kD + lane];  // scaled q, row 0
  float m = -INFINITY, lsum = 0.f, acc = 0.f;
  for (int s = start + wave; s < end; s += 4) {
    float t = qd * qkv[(size_t)s * kQKVN + kE + h * kD + lane];
    t += __shfl_xor(t, 1); t += __shfl_xor(t, 2); t += __shfl_xor(t, 4);
    t += __shfl_xor(t, 8); t += __shfl_xor(t, 16); t += __shfl_xor(t, 32);
    const float vd = qkv[(size_t)s * kQKVN + 2 * kE + h * kD + lane];
    const float mnew = fmaxf(m, t);
    const float cor = __expf(m - mnew);
    const float p = __expf(t - mnew);
    lsum = lsum * cor + p;
    acc = acc * cor + p * vd;
    m = mnew;
  }
  __shared__ float sm[4], sl[4], sa[4][64];
  sa[wave][lane] = acc;
  if (lane == 0) { sm[wave] = m; sl[wave] = lsum; }
  __syncthreads();
  if (wave == 0) {
    float M = fmaxf(fmaxf(sm[0], sm[1]), fmaxf(sm[2], sm[3]));
    float Lt = 0.f, Av = 0.f;
#pragma unroll
    for (int w = 0; w < 4; ++w) {
      const float cw = __expf(sm[w] - M);
      Lt += sl[w] * cw;
      Av += sa[w][lane] * cw;
    }
    float* p = part + ((size_t)h * kClsChunks + c) * kClsStride;
    p[lane] = Av;
    if (lane == 0) { p[64] = M; p[65] = Lt; }
  }
}

// CLS attention pass 2: combine 32 partials per head. 12 blocks x 64 lanes.
__global__ __launch_bounds__(64) void cls_combine_kernel(const float* __restrict__ part,
                                                         short* __restrict__ attn) {
  const int h = blockIdx.x;
  const int lane = threadIdx.x;
  float mc[kClsChunks], lc[kClsChunks], ac[kClsChunks];
#pragma unroll
  for (int c = 0; c < kClsChunks; ++c) {
    const float* p = part + ((size_t)h * kClsChunks + c) * kClsStride;
    mc[c] = p[64];
    lc[c] = p[65];
    ac[c] = p[lane];
  }
  float M = -INFINITY;
#pragma unroll
  for (int c = 0; c < kClsChunks; ++c) M = fmaxf(M, mc[c]);
  float L = 0.f, A = 0.f;
#pragma unroll
  for (int c = 0; c < kClsChunks; ++c) {
    const float w = __expf(mc[c] - M);
    L += lc[c] * w;
    A += ac[c] * w;
  }
  attn[h * kD + lane] = f2bf(A / L);
}

// MFMA patch attention in lattice coordinates (see round-4 notes).
__global__ __launch_bounds__(256) void patch_attn_mfma_kernel(const float* __restrict__ qkv,
                                                              short* __restrict__ attn) {
  __shared__ short Pl[4][32][104];
  const int lane = threadIdx.x & 63;
  const int wv = threadIdx.x >> 6;
  const int unit = blockIdx.x * 4 + wv;
  const int t0 = (unit & 31) * 32;
  const int res = (unit >> 5) & 3;
  const int h = unit >> 7;
  const int lrow = lane & 15;
  const int lgrp = lane >> 4;   // 0..3
  const int kg = lgrp * 8;
  const int rg = lgrp * 4;

  // ---- QK^T ----
  f32x4 s_acc[2][4] = {};
  f32x4 s_cls[2] = {};
  short8 aq[2][2];
#pragma unroll
  for (int mi = 0; mi < 2; ++mi) {
    const int tq = t0 + mi * 16 + lrow;
    const size_t row = (size_t)(4 * tq + res + 1) * kQKVN + h * kD;
#pragma unroll
    for (int ks = 0; ks < 2; ++ks)
      aq[mi][ks] = load_frag8(qkv + row + ks * 32 + kg);
  }
#pragma unroll
  for (int ni = 0; ni < 4; ++ni) {
    int u = t0 - 16 + ni * 16 + lrow;
    u = min(max(u, 0), kT - 1);  // clamp; invalid cols masked in softmax
    const size_t row = (size_t)(4 * u + res + 1) * kQKVN + kE + h * kD;
    short8 bk[2];
#pragma unroll
    for (int ks = 0; ks < 2; ++ks) bk[ks] = load_frag8(qkv + row + ks * 32 + kg);
#pragma unroll
    for (int mi = 0; mi < 2; ++mi)
#pragma unroll
      for (int ks = 0; ks < 2; ++ks)
        s_acc[mi][ni] = __builtin_amdgcn_mfma_f32_16x16x32_bf16(aq[mi][ks], bk[ks], s_acc[mi][ni], 0, 0, 0);
  }
  {  // CLS key column
    short8 bc[2] = {};
    if (lrow == 0) {
#pragma unroll
      for (int ks = 0; ks < 2; ++ks) bc[ks] = load_frag8(qkv + kE + h * kD + ks * 32 + kg);
    }
#pragma unroll
    for (int mi = 0; mi < 2; ++mi)
#pragma unroll
      for (int ks = 0; ks < 2; ++ks)
        s_cls[mi] = __builtin_amdgcn_mfma_f32_16x16x32_bf16(aq[mi][ks], bc[ks], s_cls[mi], 0, 0, 0);
  }

  // ---- zero-fill P cols 64..95 ----
#pragma unroll
  for (int i = 0; i < 2; ++i) {
    const int idx = i * 64 + lane;
    const int q = idx >> 2, ch = idx & 3;
    short8 z = {};
    *reinterpret_cast<short8*>(&Pl[wv][q][64 + ch * 8]) = z;
  }

  // ---- softmax per query row ----
#pragma unroll
  for (int mi = 0; mi < 2; ++mi) {
#pragma unroll
    for (int r = 0; r < 4; ++r) {
      const int q = mi * 16 + rg + r;
      float sw[4];
      float m = -INFINITY;
#pragma unroll
      for (int ni = 0; ni < 4; ++ni) {
        const int kk = ni * 16 + lrow;
        const int u = t0 - 16 + kk;
        const bool valid = (kk >= q) & (kk <= q + 32) & (u >= 0) & (u < kT);
        sw[ni] = valid ? s_acc[mi][ni][r] : -INFINITY;
        m = fmaxf(m, sw[ni]);
      }
      float scl = (lrow == 0) ? s_cls[mi][r] : -INFINITY;
      m = fmaxf(m, scl);
      m = fmaxf(m, __shfl_xor(m, 1)); m = fmaxf(m, __shfl_xor(m, 2));
      m = fmaxf(m, __shfl_xor(m, 4)); m = fmaxf(m, __shfl_xor(m, 8));
      float lsum = 0.f, ps[4];
#pragma unroll
      for (int ni = 0; ni < 4; ++ni) { ps[ni] = __expf(sw[ni] - m); lsum += ps[ni]; }
      const float pc = __expf(scl - m);
      lsum += pc;
      lsum += __shfl_xor(lsum, 1); lsum += __shfl_xor(lsum, 2);
      lsum += __shfl_xor(lsum, 4); lsum += __shfl_xor(lsum, 8);
      const float inv = __builtin_amdgcn_rcpf(lsum);
#pragma unroll
      for (int ni = 0; ni < 4; ++ni) Pl[wv][q][ni * 16 + lrow] = f2bf(ps[ni] * inv);
      if (lrow == 0) Pl[wv][q][64] = f2bf(pc * inv);
    }
  }

  // ---- PV ----
  f32x4 o_acc[4][2] = {};
#pragma unroll
  for (int ks = 0; ks < 3; ++ks) {
    short8 bp[2];
#pragma unroll
    for (int nq = 0; nq < 2; ++nq)
      bp[nq] = *reinterpret_cast<const short8*>(&Pl[wv][nq * 16 + lrow][ks * 32 + kg]);
    short8 av[4];
#pragma unroll
    for (int md = 0; md < 4; ++md) {
      if (ks < 2) {
        const int d = md * 16 + lrow;
#pragma unroll
        for (int e = 0; e < 8; ++e) {
          const int kk = ks * 32 + kg + e;
          int u = t0 - 16 + kk;
          u = min(max(u, 0), kT - 1);
          av[md][e] = f2bf(qkv[(size_t)(4 * u + res + 1) * kQKVN + 2 * kE + h * kD + d]);
        }
      } else {
        short8 z = {};
        av[md] = z;
        if (lgrp == 0)
          av[md][0] = f2bf(qkv[2 * kE + h * kD + md * 16 + lrow]);
      }
#pragma unroll
      for (int nq = 0; nq < 2; ++nq)
        o_acc[md][nq] = __builtin_amdgcn_mfma_f32_16x16x32_bf16(av[md], bp[nq], o_acc[md][nq], 0, 0, 0);
    }
  }

  // ---- store ----
#pragma unroll
  for (int md = 0; md < 4; ++md)
#pragma unroll
    for (int nq = 0; nq < 2; ++nq)
#pragma unroll
      for (int r = 0; r < 4; ++r) {
        const int d = md * 16 + rg + r;
        const int q = nq * 16 + lrow;
        const int s = 4 * (t0 + q) + res + 1;
        attn[(size_t)s * kE + h * kD + d] = f2bf(o_acc[md][nq][r]);
      }
}

}  // namespace

extern "C" void kernel_launch(void* const* d_in, const int* in_sizes, int n_in,
                              void* d_out, int out_size, void* d_ws, size_t ws_size,
                              hipStream_t stream) {
  const float* x = (const float*)d_in[0];
  const int* coords = (const int*)d_in[1];
  const float* qkv_w = (const float*)d_in[2];
  const float* qkv_b = (const float*)d_in[3];
  const float* out_w = (const float*)d_in[4];
  const float* out_b = (const float*)d_in[5];
  float* out = (float*)d_out;

  char* p = (char*)d_ws;
  float* qkv = (float*)p;                 p += (size_t)kS * kQKVN * sizeof(float);
  short* xb = (short*)p;                  p += (size_t)kS * kE * sizeof(short);
  short* wb = (short*)p;                  p += (size_t)kQKVN * kE * sizeof(short);
  short* owb = (short*)p;                 p += (size_t)kE * kE * sizeof(short);
  short* attnb = (short*)p;               p += (size_t)kS * kE * sizeof(short);
  float* clsp = (float*)p;                // 12*32*68 floats = 104 KB

  const int n4x = kS * kE / 4;
  const int n4w = kQKVN * kE / 4;
  const int n4o = kE * kE / 4;
  cvt_kernel<<<2048, 256, 0, stream>>>(x, xb, n4x);
  cvt_kernel<<<2048, 256, 0, stream>>>(qkv_w, wb, n4w);
  cvt_kernel<<<1024, 256, 0, stream>>>(out_w, owb, n4o);

  dim3 g1(33, 18);
  gemm_tile_kernel<<<g1, 256, 0, stream>>>(xb, wb, qkv_b, qkv, kS, kQKVN, kE);
  rope_scale_kernel<<<kS, 384, 0, stream>>>(qkv, coords);
  dim3 gc(kH, kClsChunks);
  cls_partial_kernel<<<gc, 256, 0, stream>>>(qkv, clsp);
  cls_combine_kernel<<<kH, 64, 0, stream>>>(clsp, attnb);
  patch_attn_mfma_kernel<<<384, 256, 0, stream>>>(qkv, attnb);
  dim3 g2(33, 6);
  gemm_tile_kernel<<<g2, 256, 0, stream>>>(attnb, owb, out_b, out, kS, kE, kE);
}

// Round 6
// 119.551 us; speedup vs baseline: 5.2404x; 1.0650x over previous
//
#include <hip/hip_runtime.h>
#include <hip/hip_bf16.h>

namespace {

constexpr int kS = 4097;      // sequence incl. CLS
constexpr int kL = 4096;      // patch tokens
constexpr int kE = 768;
constexpr int kH = 12;
constexpr int kD = 64;
constexpr int kQKVN = 2304;
constexpr int kT = 1024;      // lattice length per residue (kL / kDil)
constexpr int kClsChunks = 32;
constexpr int kClsStride = 68;    // 64 acc + m + l, padded
constexpr float kScale = 0.125f;  // 1/sqrt(64)

typedef short short8 __attribute__((ext_vector_type(8)));
typedef short short4v __attribute__((ext_vector_type(4)));
typedef float f32x4 __attribute__((ext_vector_type(4)));

__device__ inline short f2bf(float x) {
  __hip_bfloat16 b = __float2bfloat16(x);
  return *reinterpret_cast<short*>(&b);
}
__device__ inline float bf2f(short u) {
  unsigned int x = ((unsigned int)(unsigned short)u) << 16;
  union { unsigned int u32; float f; } c;
  c.u32 = x;
  return c.f;
}

__device__ inline void store_c(float* p, float v) { *p = v; }
__device__ inline void store_c(short* p, float v) { *p = f2bf(v); }

#define GLOAD_LDS16(g, l)                                                        \
  __builtin_amdgcn_global_load_lds(                                              \
      (const __attribute__((address_space(1))) unsigned int*)(g),                \
      (__attribute__((address_space(3))) unsigned int*)(l), 16, 0, 0)

// fp32 -> bf16 convert, x4 vectorized, grid-stride.
__global__ __launch_bounds__(256) void cvt_kernel(const float* __restrict__ in,
                                                  short* __restrict__ outp, int n4) {
  int i = blockIdx.x * blockDim.x + threadIdx.x;
  const int stride = gridDim.x * blockDim.x;
  for (; i < n4; i += stride) {
    f32x4 v = reinterpret_cast<const f32x4*>(in)[i];
    short4v o;
#pragma unroll
    for (int j = 0; j < 4; ++j) o[j] = f2bf(v[j]);
    reinterpret_cast<short4v*>(outp)[i] = o;
  }
}

// 2-phase double-buffered m97-structure GEMM (T3-minimum recipe):
// C[M][N] = A(bf16)[M][K] * W(bf16)[N][K]^T + bias(f32). 128x128 tile, BK=32,
// 4 waves (2x2), 4x4 16x16x32 fragments. STAGE(t+1) issued before compute(t);
// single vmcnt(0)+barrier per K-step (compiler drains at __syncthreads).
template <typename TC>
__global__ __launch_bounds__(256) void gemm_tile_kernel(const short* __restrict__ A,
                                                        const short* __restrict__ W,
                                                        const float* __restrict__ bias,
                                                        TC* __restrict__ C,
                                                        int Mreal, int N, int K) {
  __shared__ short Ash[2][128 * 32];
  __shared__ short Bsh[2][128 * 32];
  const int t = threadIdx.x;
  const int lane = t & 63;
  const int wave = t >> 6;
  const int wr = wave >> 1, wc = wave & 1;
  const int m0 = blockIdx.x * 128;
  const int n0 = blockIdx.y * 128;
  const int lrow = lane & 15;
  const int kg = (lane >> 4) << 3;

  const int srow = t >> 2;
  const int scol = (t & 3) << 3;
  int arow0 = m0 + srow;       if (arow0 > Mreal - 1) arow0 = Mreal - 1;
  int arow1 = m0 + 64 + srow;  if (arow1 > Mreal - 1) arow1 = Mreal - 1;
  const int brow0 = n0 + srow;
  const int brow1 = n0 + 64 + srow;

  const size_t aoff0 = (size_t)arow0 * K + scol;
  const size_t aoff1 = (size_t)arow1 * K + scol;
  const size_t boff0 = (size_t)brow0 * K + scol;
  const size_t boff1 = (size_t)brow1 * K + scol;

#define STAGE(buf, k0)                                      \
  do {                                                      \
    GLOAD_LDS16(A + aoff0 + (k0), &Ash[buf][t * 8]);        \
    GLOAD_LDS16(A + aoff1 + (k0), &Ash[buf][2048 + t * 8]); \
    GLOAD_LDS16(W + boff0 + (k0), &Bsh[buf][t * 8]);        \
    GLOAD_LDS16(W + boff1 + (k0), &Bsh[buf][2048 + t * 8]); \
  } while (0)

  f32x4 acc[4][4] = {};

  STAGE(0, 0);
  __syncthreads();  // drains vmcnt(0): tile 0 resident

  int cur = 0;
  for (int k0 = 0; k0 < K; k0 += 32) {
    if (k0 + 32 < K) STAGE(cur ^ 1, k0 + 32);  // prefetch next tile (overlaps MFMA)

    short8 a[4], b[4];
#pragma unroll
    for (int mi = 0; mi < 4; ++mi)
      a[mi] = *reinterpret_cast<const short8*>(&Ash[cur][(wr * 64 + mi * 16 + lrow) * 32 + kg]);
#pragma unroll
    for (int ni = 0; ni < 4; ++ni)
      b[ni] = *reinterpret_cast<const short8*>(&Bsh[cur][(wc * 64 + ni * 16 + lrow) * 32 + kg]);
#pragma unroll
    for (int mi = 0; mi < 4; ++mi)
#pragma unroll
      for (int ni = 0; ni < 4; ++ni)
        acc[mi][ni] = __builtin_amdgcn_mfma_f32_16x16x32_bf16(a[mi], b[ni], acc[mi][ni], 0, 0, 0);

    __syncthreads();  // drains vmcnt(0)+lgkmcnt(0): next tile resident, reads done
    cur ^= 1;
  }
#undef STAGE

  const int rg = (lane >> 4) << 2;
  for (int ni = 0; ni < 4; ++ni) {
    const int col = n0 + wc * 64 + ni * 16 + lrow;
    const float bz = bias[col];
    for (int mi = 0; mi < 4; ++mi) {
      const int rowb = m0 + wr * 64 + mi * 16 + rg;
#pragma unroll
      for (int r = 0; r < 4; ++r) {
        const int row = rowb + r;
        if (row < Mreal) store_c(&C[(size_t)row * N + col], acc[mi][ni][r] + bz);
      }
    }
  }
}

// In-place 2D RoPE on q,k patch rows of bf16 qkv[S][2304]; q rows (incl CLS)
// pre-scaled by 1/8. One block per position s; thread = (head, pair i in 0..31).
__global__ __launch_bounds__(384) void rope_scale_kernel(short* __restrict__ qkv,
                                                         const int* __restrict__ coords) {
  const int s = blockIdx.x;
  const int h = threadIdx.x >> 5;
  const int i = threadIdx.x & 31;
  unsigned int* qp = (unsigned int*)(qkv + (size_t)s * kQKVN + h * kD + 2 * i);
  const unsigned int qv = *qp;
  float x0 = bf2f((short)(qv & 0xffffu));
  float x1 = bf2f((short)(qv >> 16));
  if (s == 0) {  // CLS: no rope, just q scaling (exact pow2, no extra rounding)
    *qp = (unsigned int)(unsigned short)f2bf(x0 * kScale) |
          ((unsigned int)(unsigned short)f2bf(x1 * kScale) << 16);
    return;
  }
  const float cx = (float)coords[(s - 1) * 2] * 1e-5f;
  const float cy = (float)coords[(s - 1) * 2 + 1] * 1e-5f;
  const int j = i & 15;
  const float invf = __powf(10000.0f, -(float)j * (1.0f / 16.0f));
  const float ang = (i < 16 ? cx : cy) * invf;
  float sn, cs;
  __sincosf(ang, &sn, &cs);
  *qp = (unsigned int)(unsigned short)f2bf((x0 * cs - x1 * sn) * kScale) |
        ((unsigned int)(unsigned short)f2bf((x1 * cs + x0 * sn) * kScale) << 16);
  unsigned int* kp = qp + kE / 2;  // k block at +768 elems
  const unsigned int kv = *kp;
  x0 = bf2f((short)(kv & 0xffffu));
  x1 = bf2f((short)(kv >> 16));
  *kp = (unsigned int)(unsigned short)f2bf(x0 * cs - x1 * sn) |
        ((unsigned int)(unsigned short)f2bf(x1 * cs + x0 * sn) << 16);
}

// CLS attention, split-K pass 1: block (h, c) handles 128 keys (last chunk 129).
__global__ __launch_bounds__(256) void cls_partial_kernel(const short* __restrict__ qkv,
                                                          float* __restrict__ part) {
  const int h = blockIdx.x;
  const int c = blockIdx.y;
  const int lane = threadIdx.x & 63;
  const int wave = threadIdx.x >> 6;
  const int start = c * 128;
  const int end = (c == kClsChunks - 1) ? kS : start + 128;
  const float qd = bf2f(qkv[h * kD + lane]);  // scaled q, row 0
  float m = -INFINITY, lsum = 0.f, acc = 0.f;
  for (int s = start + wave; s < end; s += 4) {
    float t = qd * bf2f(qkv[(size_t)s * kQKVN + kE + h * kD + lane]);
    t += __shfl_xor(t, 1); t += __shfl_xor(t, 2); t += __shfl_xor(t, 4);
    t += __shfl_xor(t, 8); t += __shfl_xor(t, 16); t += __shfl_xor(t, 32);
    const float vd = bf2f(qkv[(size_t)s * kQKVN + 2 * kE + h * kD + lane]);
    const float mnew = fmaxf(m, t);
    const float cor = __expf(m - mnew);
    const float p = __expf(t - mnew);
    lsum = lsum * cor + p;
    acc = acc * cor + p * vd;
    m = mnew;
  }
  __shared__ float sm[4], sl[4], sa[4][64];
  sa[wave][lane] = acc;
  if (lane == 0) { sm[wave] = m; sl[wave] = lsum; }
  __syncthreads();
  if (wave == 0) {
    float M = fmaxf(fmaxf(sm[0], sm[1]), fmaxf(sm[2], sm[3]));
    float Lt = 0.f, Av = 0.f;
#pragma unroll
    for (int w = 0; w < 4; ++w) {
      const float cw = __expf(sm[w] - M);
      Lt += sl[w] * cw;
      Av += sa[w][lane] * cw;
    }
    float* p = part + ((size_t)h * kClsChunks + c) * kClsStride;
    p[lane] = Av;
    if (lane == 0) { p[64] = M; p[65] = Lt; }
  }
}

// CLS attention pass 2: combine 32 partials per head. 12 blocks x 64 lanes.
__global__ __launch_bounds__(64) void cls_combine_kernel(const float* __restrict__ part,
                                                         short* __restrict__ attn) {
  const int h = blockIdx.x;
  const int lane = threadIdx.x;
  float mc[kClsChunks], lc[kClsChunks], ac[kClsChunks];
#pragma unroll
  for (int c = 0; c < kClsChunks; ++c) {
    const float* p = part + ((size_t)h * kClsChunks + c) * kClsStride;
    mc[c] = p[64];
    lc[c] = p[65];
    ac[c] = p[lane];
  }
  float M = -INFINITY;
#pragma unroll
  for (int c = 0; c < kClsChunks; ++c) M = fmaxf(M, mc[c]);
  float L = 0.f, A = 0.f;
#pragma unroll
  for (int c = 0; c < kClsChunks; ++c) {
    const float w = __expf(mc[c] - M);
    L += lc[c] * w;
    A += ac[c] * w;
  }
  attn[h * kD + lane] = f2bf(A / L);
}

// MFMA patch attention in lattice coordinates, bf16 qkv input.
// l = 4t + res; query (h,res,t) attends lattice keys u in [t-16,t+16] + CLS.
__global__ __launch_bounds__(256) void patch_attn_mfma_kernel(const short* __restrict__ qkv,
                                                              short* __restrict__ attn) {
  __shared__ short Pl[4][32][104];
  const int lane = threadIdx.x & 63;
  const int wv = threadIdx.x >> 6;
  const int unit = blockIdx.x * 4 + wv;
  const int t0 = (unit & 31) * 32;
  const int res = (unit >> 5) & 3;
  const int h = unit >> 7;
  const int lrow = lane & 15;
  const int lgrp = lane >> 4;   // 0..3
  const int kg = lgrp * 8;
  const int rg = lgrp * 4;

  // ---- QK^T ----
  f32x4 s_acc[2][4] = {};
  f32x4 s_cls[2] = {};
  short8 aq[2][2];
#pragma unroll
  for (int mi = 0; mi < 2; ++mi) {
    const int tq = t0 + mi * 16 + lrow;
    const size_t row = (size_t)(4 * tq + res + 1) * kQKVN + h * kD;
#pragma unroll
    for (int ks = 0; ks < 2; ++ks)
      aq[mi][ks] = *reinterpret_cast<const short8*>(qkv + row + ks * 32 + kg);
  }
#pragma unroll
  for (int ni = 0; ni < 4; ++ni) {
    int u = t0 - 16 + ni * 16 + lrow;
    u = min(max(u, 0), kT - 1);  // clamp; invalid cols masked in softmax
    const size_t row = (size_t)(4 * u + res + 1) * kQKVN + kE + h * kD;
    short8 bk[2];
#pragma unroll
    for (int ks = 0; ks < 2; ++ks)
      bk[ks] = *reinterpret_cast<const short8*>(qkv + row + ks * 32 + kg);
#pragma unroll
    for (int mi = 0; mi < 2; ++mi)
#pragma unroll
      for (int ks = 0; ks < 2; ++ks)
        s_acc[mi][ni] = __builtin_amdgcn_mfma_f32_16x16x32_bf16(aq[mi][ks], bk[ks], s_acc[mi][ni], 0, 0, 0);
  }
  {  // CLS key column
    short8 bc[2] = {};
    if (lrow == 0) {
#pragma unroll
      for (int ks = 0; ks < 2; ++ks)
        bc[ks] = *reinterpret_cast<const short8*>(qkv + kE + h * kD + ks * 32 + kg);
    }
#pragma unroll
    for (int mi = 0; mi < 2; ++mi)
#pragma unroll
      for (int ks = 0; ks < 2; ++ks)
        s_cls[mi] = __builtin_amdgcn_mfma_f32_16x16x32_bf16(aq[mi][ks], bc[ks], s_cls[mi], 0, 0, 0);
  }

  // ---- zero-fill P cols 64..95 ----
#pragma unroll
  for (int i = 0; i < 2; ++i) {
    const int idx = i * 64 + lane;
    const int q = idx >> 2, ch = idx & 3;
    short8 z = {};
    *reinterpret_cast<short8*>(&Pl[wv][q][64 + ch * 8]) = z;
  }

  // ---- softmax per query row (C-layout), write normalized P ----
#pragma unroll
  for (int mi = 0; mi < 2; ++mi) {
#pragma unroll
    for (int r = 0; r < 4; ++r) {
      const int q = mi * 16 + rg + r;
      float sw[4];
      float m = -INFINITY;
#pragma unroll
      for (int ni = 0; ni < 4; ++ni) {
        const int kk = ni * 16 + lrow;
        const int u = t0 - 16 + kk;
        const bool valid = (kk >= q) & (kk <= q + 32) & (u >= 0) & (u < kT);
        sw[ni] = valid ? s_acc[mi][ni][r] : -INFINITY;
        m = fmaxf(m, sw[ni]);
      }
      float scl = (lrow == 0) ? s_cls[mi][r] : -INFINITY;
      m = fmaxf(m, scl);
      m = fmaxf(m, __shfl_xor(m, 1)); m = fmaxf(m, __shfl_xor(m, 2));
      m = fmaxf(m, __shfl_xor(m, 4)); m = fmaxf(m, __shfl_xor(m, 8));
      float lsum = 0.f, ps[4];
#pragma unroll
      for (int ni = 0; ni < 4; ++ni) { ps[ni] = __expf(sw[ni] - m); lsum += ps[ni]; }
      const float pc = __expf(scl - m);
      lsum += pc;
      lsum += __shfl_xor(lsum, 1); lsum += __shfl_xor(lsum, 2);
      lsum += __shfl_xor(lsum, 4); lsum += __shfl_xor(lsum, 8);
      const float inv = __builtin_amdgcn_rcpf(lsum);
#pragma unroll
      for (int ni = 0; ni < 4; ++ni) Pl[wv][q][ni * 16 + lrow] = f2bf(ps[ni] * inv);
      if (lrow == 0) Pl[wv][q][64] = f2bf(pc * inv);
    }
  }

  // ---- PV: out[d][q] += V^T[d][kk] * P[q][kk] ----
  f32x4 o_acc[4][2] = {};
#pragma unroll
  for (int ks = 0; ks < 3; ++ks) {
    short8 bp[2];
#pragma unroll
    for (int nq = 0; nq < 2; ++nq)
      bp[nq] = *reinterpret_cast<const short8*>(&Pl[wv][nq * 16 + lrow][ks * 32 + kg]);
    short8 av[4];
#pragma unroll
    for (int md = 0; md < 4; ++md) {
      if (ks < 2) {
        const int d = md * 16 + lrow;
#pragma unroll
        for (int e = 0; e < 8; ++e) {
          const int kk = ks * 32 + kg + e;
          int u = t0 - 16 + kk;
          u = min(max(u, 0), kT - 1);  // invalid kk have P==0
          av[md][e] = qkv[(size_t)(4 * u + res + 1) * kQKVN + 2 * kE + h * kD + d];
        }
      } else {
        short8 z = {};
        av[md] = z;
        if (lgrp == 0)  // kk==64 -> v_cls
          av[md][0] = qkv[2 * kE + h * kD + md * 16 + lrow];
      }
#pragma unroll
      for (int nq = 0; nq < 2; ++nq)
        o_acc[md][nq] = __builtin_amdgcn_mfma_f32_16x16x32_bf16(av[md], bp[nq], o_acc[md][nq], 0, 0, 0);
    }
  }

  // ---- store ----
#pragma unroll
  for (int md = 0; md < 4; ++md)
#pragma unroll
    for (int nq = 0; nq < 2; ++nq)
#pragma unroll
      for (int r = 0; r < 4; ++r) {
        const int d = md * 16 + rg + r;
        const int q = nq * 16 + lrow;
        const int s = 4 * (t0 + q) + res + 1;
        attn[(size_t)s * kE + h * kD + d] = f2bf(o_acc[md][nq][r]);
      }
}

}  // namespace

extern "C" void kernel_launch(void* const* d_in, const int* in_sizes, int n_in,
                              void* d_out, int out_size, void* d_ws, size_t ws_size,
                              hipStream_t stream) {
  const float* x = (const float*)d_in[0];
  const int* coords = (const int*)d_in[1];
  const float* qkv_w = (const float*)d_in[2];
  const float* qkv_b = (const float*)d_in[3];
  const float* out_w = (const float*)d_in[4];
  const float* out_b = (const float*)d_in[5];
  float* out = (float*)d_out;

  char* p = (char*)d_ws;
  short* qkvb = (short*)p;                p += (size_t)kS * kQKVN * sizeof(short);  // 18.9 MB
  short* xb = (short*)p;                  p += (size_t)kS * kE * sizeof(short);     // 6.3 MB
  short* wb = (short*)p;                  p += (size_t)kQKVN * kE * sizeof(short);  // 3.5 MB
  short* owb = (short*)p;                 p += (size_t)kE * kE * sizeof(short);     // 1.2 MB
  short* attnb = (short*)p;               p += (size_t)kS * kE * sizeof(short);     // 6.3 MB
  float* clsp = (float*)p;                // 12*32*68 floats = 104 KB

  const int n4x = kS * kE / 4;
  const int n4w = kQKVN * kE / 4;
  const int n4o = kE * kE / 4;
  cvt_kernel<<<2048, 256, 0, stream>>>(x, xb, n4x);
  cvt_kernel<<<2048, 256, 0, stream>>>(qkv_w, wb, n4w);
  cvt_kernel<<<1024, 256, 0, stream>>>(out_w, owb, n4o);

  dim3 g1(33, 18);
  gemm_tile_kernel<short><<<g1, 256, 0, stream>>>(xb, wb, qkv_b, qkvb, kS, kQKVN, kE);
  rope_scale_kernel<<<kS, 384, 0, stream>>>(qkvb, coords);
  dim3 gc(kH, kClsChunks);
  cls_partial_kernel<<<gc, 256, 0, stream>>>(qkvb, clsp);
  cls_combine_kernel<<<kH, 64, 0, stream>>>(clsp, attnb);
  patch_attn_mfma_kernel<<<384, 256, 0, stream>>>(qkvb, attnb);
  dim3 g2(33, 6);
  gemm_tile_kernel<float><<<g2, 256, 0, stream>>>(attnb, owb, out_b, out, kS, kE, kE);
}

// Round 7
// 104.661 us; speedup vs baseline: 5.9860x; 1.1423x over previous
//
#include <hip/hip_runtime.h>
#include <hip/hip_bf16.h>

namespace {

constexpr int kS = 4097;      // sequence incl. CLS
constexpr int kL = 4096;      // patch tokens
constexpr int kE = 768;
constexpr int kH = 12;
constexpr int kD = 64;
constexpr int kQKVN = 2304;
constexpr int kT = 1024;      // lattice length per residue (kL / kDil)
constexpr int kClsChunks = 32;
constexpr int kClsStride = 68;    // 64 acc + m + l, padded
constexpr float kScale = 0.125f;  // 1/sqrt(64)

typedef short short8 __attribute__((ext_vector_type(8)));
typedef short short4v __attribute__((ext_vector_type(4)));
typedef float f32x4 __attribute__((ext_vector_type(4)));

__device__ inline short f2bf(float x) {
  __hip_bfloat16 b = __float2bfloat16(x);
  return *reinterpret_cast<short*>(&b);
}
__device__ inline float bf2f(short u) {
  unsigned int x = ((unsigned int)(unsigned short)u) << 16;
  union { unsigned int u32; float f; } c;
  c.u32 = x;
  return c.f;
}

__device__ inline void store_c(float* p, float v) { *p = v; }
__device__ inline void store_c(short* p, float v) { *p = f2bf(v); }

#define GLOAD_LDS16(g, l)                                                        \
  __builtin_amdgcn_global_load_lds(                                              \
      (const __attribute__((address_space(1))) unsigned int*)(g),                \
      (__attribute__((address_space(3))) unsigned int*)(l), 16, 0, 0)

// Fused fp32->bf16 convert of x, qkv_w, out_w in one grid-stride kernel.
__global__ __launch_bounds__(256) void cvt3_kernel(const float* __restrict__ x,
                                                   const float* __restrict__ w,
                                                   const float* __restrict__ ow,
                                                   short* __restrict__ xb,
                                                   short* __restrict__ wb,
                                                   short* __restrict__ owb,
                                                   int n4x, int n4w, int n4o) {
  const int total = n4x + n4w + n4o;
  int i = blockIdx.x * blockDim.x + threadIdx.x;
  const int stride = gridDim.x * blockDim.x;
  for (; i < total; i += stride) {
    const float* src;
    short* dst;
    int k;
    if (i < n4x) { src = x; dst = xb; k = i; }
    else if (i < n4x + n4w) { src = w; dst = wb; k = i - n4x; }
    else { src = ow; dst = owb; k = i - n4x - n4w; }
    f32x4 v = reinterpret_cast<const f32x4*>(src)[k];
    short4v o;
#pragma unroll
    for (int j = 0; j < 4; ++j) o[j] = f2bf(v[j]);
    reinterpret_cast<short4v*>(dst)[k] = o;
  }
}

// 2-phase double-buffered GEMM. C[M][N] = A(bf16)*W(bf16)^T + bias(f32).
// 128x128 tile, BK=32, 4 waves (2x2), 4x4 16x16x32 fragments.
// ROPE: apply 2D rope + q-scale to q/k columns in the epilogue (QKV GEMM).
// Rotation pairs (2i,2i+1) are adjacent lrow lanes -> shfl_xor(v,1).
template <bool ROPE, typename TC>
__global__ __launch_bounds__(256) void gemm_tile_kernel(const short* __restrict__ A,
                                                        const short* __restrict__ W,
                                                        const float* __restrict__ bias,
                                                        TC* __restrict__ C,
                                                        int Mreal, int N, int K,
                                                        const int* __restrict__ coords) {
  __shared__ short Ash[2][128 * 32];
  __shared__ short Bsh[2][128 * 32];
  const int t = threadIdx.x;
  const int lane = t & 63;
  const int wave = t >> 6;
  const int wr = wave >> 1, wc = wave & 1;
  const int m0 = blockIdx.x * 128;
  const int n0 = blockIdx.y * 128;
  const int lrow = lane & 15;
  const int kg = (lane >> 4) << 3;

  const int srow = t >> 2;
  const int scol = (t & 3) << 3;
  int arow0 = m0 + srow;       if (arow0 > Mreal - 1) arow0 = Mreal - 1;
  int arow1 = m0 + 64 + srow;  if (arow1 > Mreal - 1) arow1 = Mreal - 1;
  const int brow0 = n0 + srow;
  const int brow1 = n0 + 64 + srow;

  const size_t aoff0 = (size_t)arow0 * K + scol;
  const size_t aoff1 = (size_t)arow1 * K + scol;
  const size_t boff0 = (size_t)brow0 * K + scol;
  const size_t boff1 = (size_t)brow1 * K + scol;

#define STAGE(buf, k0)                                      \
  do {                                                      \
    GLOAD_LDS16(A + aoff0 + (k0), &Ash[buf][t * 8]);        \
    GLOAD_LDS16(A + aoff1 + (k0), &Ash[buf][2048 + t * 8]); \
    GLOAD_LDS16(W + boff0 + (k0), &Bsh[buf][t * 8]);        \
    GLOAD_LDS16(W + boff1 + (k0), &Bsh[buf][2048 + t * 8]); \
  } while (0)

  f32x4 acc[4][4] = {};

  STAGE(0, 0);
  __syncthreads();  // tile 0 resident

  int cur = 0;
  for (int k0 = 0; k0 < K; k0 += 32) {
    if (k0 + 32 < K) STAGE(cur ^ 1, k0 + 32);  // prefetch overlaps MFMA

    short8 a[4], b[4];
#pragma unroll
    for (int mi = 0; mi < 4; ++mi)
      a[mi] = *reinterpret_cast<const short8*>(&Ash[cur][(wr * 64 + mi * 16 + lrow) * 32 + kg]);
#pragma unroll
    for (int ni = 0; ni < 4; ++ni)
      b[ni] = *reinterpret_cast<const short8*>(&Bsh[cur][(wc * 64 + ni * 16 + lrow) * 32 + kg]);
#pragma unroll
    for (int mi = 0; mi < 4; ++mi)
#pragma unroll
      for (int ni = 0; ni < 4; ++ni)
        acc[mi][ni] = __builtin_amdgcn_mfma_f32_16x16x32_bf16(a[mi], b[ni], acc[mi][ni], 0, 0, 0);

    __syncthreads();
    cur ^= 1;
  }
#undef STAGE

  // Epilogue. C/D layout (m89): col = lane&15, row = (lane>>4)*4 + reg.
  const int rg = (lane >> 4) << 2;
  for (int ni = 0; ni < 4; ++ni) {
    const int col = n0 + wc * 64 + ni * 16 + lrow;
    const float bz = bias[col];
    const int sec = col / 768;  // 0=q 1=k 2=v; uniform per ni (768%16==0)
    // per-lane rope params (only used for q/k)
    const int dh = col & 63;
    const bool odd = dh & 1;
    const int jf = (dh >> 1) & 15;
    const bool usex = (dh >> 1) < 16;
    const float invf = __powf(10000.0f, -(float)jf * (1.0f / 16.0f));
    for (int mi = 0; mi < 4; ++mi) {
      const int rowb = m0 + wr * 64 + mi * 16 + rg;
#pragma unroll
      for (int r = 0; r < 4; ++r) {
        const int row = rowb + r;
        float v = acc[mi][ni][r] + bz;
        if (ROPE && sec != 2) {
          const float partner = __shfl_xor(v, 1);  // pair element (w/ its bias)
          float cs = 1.f, sn = 0.f;
          if (row > 0) {  // uniform within 16-lane group
            const int cl = min(row, kS - 1) - 1;
            const float cx = (float)coords[cl * 2] * 1e-5f;
            const float cy = (float)coords[cl * 2 + 1] * 1e-5f;
            __sincosf((usex ? cx : cy) * invf, &sn, &cs);
          }
          v = odd ? (v * cs + partner * sn) : (v * cs - partner * sn);
          if (sec == 0) v *= kScale;  // q pre-scaled (incl CLS row)
        }
        if (row < Mreal) store_c(&C[(size_t)row * N + col], v);
      }
    }
  }
}

// Fused attention kernel:
//  blocks [0,384):   MFMA patch attention (lattice coords), 4 waves = 4 units
//  blocks [384,768): CLS split-K partials (h = idx>>5, chunk = idx&31)
__global__ __launch_bounds__(256) void attn_kernel(const short* __restrict__ qkv,
                                                   short* __restrict__ attn,
                                                   float* __restrict__ part) {
  __shared__ short Pl[4][32][104];
  __shared__ float sm[4], sl[4], sa[4][64];
  const int lane = threadIdx.x & 63;
  const int wv = threadIdx.x >> 6;

  if (blockIdx.x >= 384) {  // ---------- CLS partial ----------
    const int idx = blockIdx.x - 384;
    const int h = idx >> 5;
    const int c = idx & 31;
    const int start = c * 128;
    const int end = (c == kClsChunks - 1) ? kS : start + 128;
    const float qd = bf2f(qkv[h * kD + lane]);  // scaled q, row 0
    float m = -INFINITY, lsum = 0.f, acc = 0.f;
    for (int s = start + wv; s < end; s += 4) {
      float tt = qd * bf2f(qkv[(size_t)s * kQKVN + kE + h * kD + lane]);
      tt += __shfl_xor(tt, 1); tt += __shfl_xor(tt, 2); tt += __shfl_xor(tt, 4);
      tt += __shfl_xor(tt, 8); tt += __shfl_xor(tt, 16); tt += __shfl_xor(tt, 32);
      const float vd = bf2f(qkv[(size_t)s * kQKVN + 2 * kE + h * kD + lane]);
      const float mnew = fmaxf(m, tt);
      const float cor = __expf(m - mnew);
      const float p = __expf(tt - mnew);
      lsum = lsum * cor + p;
      acc = acc * cor + p * vd;
      m = mnew;
    }
    sa[wv][lane] = acc;
    if (lane == 0) { sm[wv] = m; sl[wv] = lsum; }
    __syncthreads();
    if (wv == 0) {
      float M = fmaxf(fmaxf(sm[0], sm[1]), fmaxf(sm[2], sm[3]));
      float Lt = 0.f, Av = 0.f;
#pragma unroll
      for (int w = 0; w < 4; ++w) {
        const float cw = __expf(sm[w] - M);
        Lt += sl[w] * cw;
        Av += sa[w][lane] * cw;
      }
      float* p = part + ((size_t)h * kClsChunks + c) * kClsStride;
      p[lane] = Av;
      if (lane == 0) { p[64] = M; p[65] = Lt; }
    }
    return;
  }

  // ---------- patch attention ----------
  const int unit = blockIdx.x * 4 + wv;
  const int t0 = (unit & 31) * 32;
  const int res = (unit >> 5) & 3;
  const int h = unit >> 7;
  const int lrow = lane & 15;
  const int lgrp = lane >> 4;
  const int kg = lgrp * 8;
  const int rg = lgrp * 4;

  // ---- QK^T ----
  f32x4 s_acc[2][4] = {};
  f32x4 s_cls[2] = {};
  short8 aq[2][2];
#pragma unroll
  for (int mi = 0; mi < 2; ++mi) {
    const int tq = t0 + mi * 16 + lrow;
    const size_t row = (size_t)(4 * tq + res + 1) * kQKVN + h * kD;
#pragma unroll
    for (int ks = 0; ks < 2; ++ks)
      aq[mi][ks] = *reinterpret_cast<const short8*>(qkv + row + ks * 32 + kg);
  }
#pragma unroll
  for (int ni = 0; ni < 4; ++ni) {
    int u = t0 - 16 + ni * 16 + lrow;
    u = min(max(u, 0), kT - 1);  // clamp; invalid cols masked in softmax
    const size_t row = (size_t)(4 * u + res + 1) * kQKVN + kE + h * kD;
    short8 bk[2];
#pragma unroll
    for (int ks = 0; ks < 2; ++ks)
      bk[ks] = *reinterpret_cast<const short8*>(qkv + row + ks * 32 + kg);
#pragma unroll
    for (int mi = 0; mi < 2; ++mi)
#pragma unroll
      for (int ks = 0; ks < 2; ++ks)
        s_acc[mi][ni] = __builtin_amdgcn_mfma_f32_16x16x32_bf16(aq[mi][ks], bk[ks], s_acc[mi][ni], 0, 0, 0);
  }
  {  // CLS key column
    short8 bc[2] = {};
    if (lrow == 0) {
#pragma unroll
      for (int ks = 0; ks < 2; ++ks)
        bc[ks] = *reinterpret_cast<const short8*>(qkv + kE + h * kD + ks * 32 + kg);
    }
#pragma unroll
    for (int mi = 0; mi < 2; ++mi)
#pragma unroll
      for (int ks = 0; ks < 2; ++ks)
        s_cls[mi] = __builtin_amdgcn_mfma_f32_16x16x32_bf16(aq[mi][ks], bc[ks], s_cls[mi], 0, 0, 0);
  }

  // ---- zero-fill P cols 64..95 ----
#pragma unroll
  for (int i = 0; i < 2; ++i) {
    const int idx = i * 64 + lane;
    const int q = idx >> 2, ch = idx & 3;
    short8 z = {};
    *reinterpret_cast<short8*>(&Pl[wv][q][64 + ch * 8]) = z;
  }

  // ---- softmax per query row (C-layout), write normalized P ----
#pragma unroll
  for (int mi = 0; mi < 2; ++mi) {
#pragma unroll
    for (int r = 0; r < 4; ++r) {
      const int q = mi * 16 + rg + r;
      float sw[4];
      float m = -INFINITY;
#pragma unroll
      for (int ni = 0; ni < 4; ++ni) {
        const int kk = ni * 16 + lrow;
        const int u = t0 - 16 + kk;
        const bool valid = (kk >= q) & (kk <= q + 32) & (u >= 0) & (u < kT);
        sw[ni] = valid ? s_acc[mi][ni][r] : -INFINITY;
        m = fmaxf(m, sw[ni]);
      }
      float scl = (lrow == 0) ? s_cls[mi][r] : -INFINITY;
      m = fmaxf(m, scl);
      m = fmaxf(m, __shfl_xor(m, 1)); m = fmaxf(m, __shfl_xor(m, 2));
      m = fmaxf(m, __shfl_xor(m, 4)); m = fmaxf(m, __shfl_xor(m, 8));
      float lsum = 0.f, ps[4];
#pragma unroll
      for (int ni = 0; ni < 4; ++ni) { ps[ni] = __expf(sw[ni] - m); lsum += ps[ni]; }
      const float pc = __expf(scl - m);
      lsum += pc;
      lsum += __shfl_xor(lsum, 1); lsum += __shfl_xor(lsum, 2);
      lsum += __shfl_xor(lsum, 4); lsum += __shfl_xor(lsum, 8);
      const float inv = __builtin_amdgcn_rcpf(lsum);
#pragma unroll
      for (int ni = 0; ni < 4; ++ni) Pl[wv][q][ni * 16 + lrow] = f2bf(ps[ni] * inv);
      if (lrow == 0) Pl[wv][q][64] = f2bf(pc * inv);
    }
  }

  // ---- PV: out[d][q] += V^T[d][kk] * P[q][kk] ----
  f32x4 o_acc[4][2] = {};
#pragma unroll
  for (int ks = 0; ks < 3; ++ks) {
    short8 bp[2];
#pragma unroll
    for (int nq = 0; nq < 2; ++nq)
      bp[nq] = *reinterpret_cast<const short8*>(&Pl[wv][nq * 16 + lrow][ks * 32 + kg]);
    short8 av[4];
#pragma unroll
    for (int md = 0; md < 4; ++md) {
      if (ks < 2) {
        const int d = md * 16 + lrow;
#pragma unroll
        for (int e = 0; e < 8; ++e) {
          const int kk = ks * 32 + kg + e;
          int u = t0 - 16 + kk;
          u = min(max(u, 0), kT - 1);  // invalid kk have P==0
          av[md][e] = qkv[(size_t)(4 * u + res + 1) * kQKVN + 2 * kE + h * kD + d];
        }
      } else {
        short8 z = {};
        av[md] = z;
        if (lgrp == 0)  // kk==64 -> v_cls
          av[md][0] = qkv[2 * kE + h * kD + md * 16 + lrow];
      }
#pragma unroll
      for (int nq = 0; nq < 2; ++nq)
        o_acc[md][nq] = __builtin_amdgcn_mfma_f32_16x16x32_bf16(av[md], bp[nq], o_acc[md][nq], 0, 0, 0);
    }
  }

  // ---- store ----
#pragma unroll
  for (int md = 0; md < 4; ++md)
#pragma unroll
    for (int nq = 0; nq < 2; ++nq)
#pragma unroll
      for (int r = 0; r < 4; ++r) {
        const int d = md * 16 + rg + r;
        const int q = nq * 16 + lrow;
        const int s = 4 * (t0 + q) + res + 1;
        attn[(size_t)s * kE + h * kD + d] = f2bf(o_acc[md][nq][r]);
      }
}

// CLS attention pass 2: combine 32 partials per head. 12 blocks x 64 lanes.
__global__ __launch_bounds__(64) void cls_combine_kernel(const float* __restrict__ part,
                                                         short* __restrict__ attn) {
  const int h = blockIdx.x;
  const int lane = threadIdx.x;
  float mc[kClsChunks], lc[kClsChunks], ac[kClsChunks];
#pragma unroll
  for (int c = 0; c < kClsChunks; ++c) {
    const float* p = part + ((size_t)h * kClsChunks + c) * kClsStride;
    mc[c] = p[64];
    lc[c] = p[65];
    ac[c] = p[lane];
  }
  float M = -INFINITY;
#pragma unroll
  for (int c = 0; c < kClsChunks; ++c) M = fmaxf(M, mc[c]);
  float L = 0.f, A = 0.f;
#pragma unroll
  for (int c = 0; c < kClsChunks; ++c) {
    const float w = __expf(mc[c] - M);
    L += lc[c] * w;
    A += ac[c] * w;
  }
  attn[h * kD + lane] = f2bf(A / L);
}

}  // namespace

extern "C" void kernel_launch(void* const* d_in, const int* in_sizes, int n_in,
                              void* d_out, int out_size, void* d_ws, size_t ws_size,
                              hipStream_t stream) {
  const float* x = (const float*)d_in[0];
  const int* coords = (const int*)d_in[1];
  const float* qkv_w = (const float*)d_in[2];
  const float* qkv_b = (const float*)d_in[3];
  const float* out_w = (const float*)d_in[4];
  const float* out_b = (const float*)d_in[5];
  float* out = (float*)d_out;

  char* p = (char*)d_ws;
  short* qkvb = (short*)p;                p += (size_t)kS * kQKVN * sizeof(short);  // 18.9 MB
  short* xb = (short*)p;                  p += (size_t)kS * kE * sizeof(short);     // 6.3 MB
  short* wb = (short*)p;                  p += (size_t)kQKVN * kE * sizeof(short);  // 3.5 MB
  short* owb = (short*)p;                 p += (size_t)kE * kE * sizeof(short);     // 1.2 MB
  short* attnb = (short*)p;               p += (size_t)kS * kE * sizeof(short);     // 6.3 MB
  float* clsp = (float*)p;                // 12*32*68 floats = 104 KB

  const int n4x = kS * kE / 4;
  const int n4w = kQKVN * kE / 4;
  const int n4o = kE * kE / 4;
  cvt3_kernel<<<2048, 256, 0, stream>>>(x, qkv_w, out_w, xb, wb, owb, n4x, n4w, n4o);

  dim3 g1(33, 18);  // ceil(4097/128), 2304/128
  gemm_tile_kernel<true, short><<<g1, 256, 0, stream>>>(xb, wb, qkv_b, qkvb, kS, kQKVN, kE, coords);
  attn_kernel<<<768, 256, 0, stream>>>(qkvb, attnb, clsp);
  cls_combine_kernel<<<kH, 64, 0, stream>>>(clsp, attnb);
  dim3 g2(33, 6);   // ceil(4097/128), 768/128
  gemm_tile_kernel<false, float><<<g2, 256, 0, stream>>>(attnb, owb, out_b, out, kS, kE, kE, nullptr);
}

// Round 8
// 104.446 us; speedup vs baseline: 5.9983x; 1.0021x over previous
//
#include <hip/hip_runtime.h>
#include <hip/hip_bf16.h>

namespace {

constexpr int kS = 4097;      // sequence incl. CLS
constexpr int kL = 4096;      // patch tokens
constexpr int kE = 768;
constexpr int kH = 12;
constexpr int kD = 64;
constexpr int kQKVN = 2304;
constexpr int kT = 1024;      // lattice length per residue (kL / kDil)
constexpr int kClsChunks = 32;
constexpr int kClsStride = 68;    // 64 acc + m + l, padded
constexpr float kScale = 0.125f;  // 1/sqrt(64)

typedef short short8 __attribute__((ext_vector_type(8)));
typedef short short4v __attribute__((ext_vector_type(4)));
typedef float f32x4 __attribute__((ext_vector_type(4)));

__device__ inline short f2bf(float x) {
  __hip_bfloat16 b = __float2bfloat16(x);
  return *reinterpret_cast<short*>(&b);
}
__device__ inline float bf2f(short u) {
  unsigned int x = ((unsigned int)(unsigned short)u) << 16;
  union { unsigned int u32; float f; } c;
  c.u32 = x;
  return c.f;
}

__device__ inline void store_c(float* p, float v) { *p = v; }
__device__ inline void store_c(short* p, float v) { *p = f2bf(v); }

#define GLOAD_LDS16(g, l)                                                        \
  __builtin_amdgcn_global_load_lds(                                              \
      (const __attribute__((address_space(1))) unsigned int*)(g),                \
      (__attribute__((address_space(3))) unsigned int*)(l), 16, 0, 0)

// Fused fp32->bf16 convert of x, qkv_w, out_w in one grid-stride kernel.
__global__ __launch_bounds__(256) void cvt3_kernel(const float* __restrict__ x,
                                                   const float* __restrict__ w,
                                                   const float* __restrict__ ow,
                                                   short* __restrict__ xb,
                                                   short* __restrict__ wb,
                                                   short* __restrict__ owb,
                                                   int n4x, int n4w, int n4o) {
  const int total = n4x + n4w + n4o;
  int i = blockIdx.x * blockDim.x + threadIdx.x;
  const int stride = gridDim.x * blockDim.x;
  for (; i < total; i += stride) {
    const float* src;
    short* dst;
    int k;
    if (i < n4x) { src = x; dst = xb; k = i; }
    else if (i < n4x + n4w) { src = w; dst = wb; k = i - n4x; }
    else { src = ow; dst = owb; k = i - n4x - n4w; }
    f32x4 v = reinterpret_cast<const f32x4*>(src)[k];
    short4v o;
#pragma unroll
    for (int j = 0; j < 4; ++j) o[j] = f2bf(v[j]);
    reinterpret_cast<short4v*>(dst)[k] = o;
  }
}

// Counted-vmcnt ring-pipelined GEMM (T4 on the minimum template, m201 primitives):
// C[M][N] = A(bf16)*W(bf16)^T + bias(f32). 128x128 tile, BK=32, 4 waves (2x2),
// 4x4 16x16x32 fragments. 3-buffer LDS ring, prefetch depth 2,
// s_waitcnt vmcnt(4) (never 0 mid-loop) + raw s_barrier. K%32==0, N%128==0.
// ROPE: 2D rope + q-scale fused into the QKV-GEMM epilogue.
template <bool ROPE, typename TC>
__global__ __launch_bounds__(256) void gemm_tile_kernel(const short* __restrict__ A,
                                                        const short* __restrict__ W,
                                                        const float* __restrict__ bias,
                                                        TC* __restrict__ C,
                                                        int Mreal, int N, int K,
                                                        const int* __restrict__ coords) {
  __shared__ short Ash[3][128 * 32];
  __shared__ short Bsh[3][128 * 32];
  const int t = threadIdx.x;
  const int lane = t & 63;
  const int wave = t >> 6;
  const int wr = wave >> 1, wc = wave & 1;
  const int m0 = blockIdx.x * 128;
  const int n0 = blockIdx.y * 128;
  const int lrow = lane & 15;
  const int kg = (lane >> 4) << 3;

  const int srow = t >> 2;
  const int scol = (t & 3) << 3;
  int arow0 = m0 + srow;       if (arow0 > Mreal - 1) arow0 = Mreal - 1;
  int arow1 = m0 + 64 + srow;  if (arow1 > Mreal - 1) arow1 = Mreal - 1;
  const int brow0 = n0 + srow;
  const int brow1 = n0 + 64 + srow;

  const size_t aoff0 = (size_t)arow0 * K + scol;
  const size_t aoff1 = (size_t)arow1 * K + scol;
  const size_t boff0 = (size_t)brow0 * K + scol;
  const size_t boff1 = (size_t)brow1 * K + scol;

#define STAGE(buf, k0)                                        \
  do {                                                        \
    GLOAD_LDS16(A + aoff0 + (k0), &Ash[buf][t * 8]);          \
    GLOAD_LDS16(A + aoff1 + (k0), &Ash[buf][2048 + t * 8]);   \
    GLOAD_LDS16(W + boff0 + (k0), &Bsh[buf][t * 8]);          \
    GLOAD_LDS16(W + boff1 + (k0), &Bsh[buf][2048 + t * 8]);   \
  } while (0)

  f32x4 acc[4][4] = {};
  const int nsteps = K / 32;

  STAGE(0, 0);
  if (nsteps > 1) STAGE(1, 32);

  int rbuf = 0;   // buffer consumed this iteration
  int sbuf = 2;   // buffer staged this iteration (for step tt+2)
  for (int tt = 0; tt < nsteps; ++tt) {
    // Wait for the OLDEST stage (buf rbuf) only; keep up to 4 loads in flight.
    if (tt + 1 < nsteps) {
      asm volatile("s_waitcnt vmcnt(4)" ::: "memory");
    } else {
      asm volatile("s_waitcnt vmcnt(0)" ::: "memory");
    }
    __builtin_amdgcn_s_barrier();          // raw barrier: no vmcnt(0) drain
    __builtin_amdgcn_sched_barrier(0);     // pin: nothing crosses the barrier

    if (tt + 2 < nsteps) STAGE(sbuf, (tt + 2) * 32);  // issue early, lands later

    short8 a[4], b[4];
#pragma unroll
    for (int mi = 0; mi < 4; ++mi)
      a[mi] = *reinterpret_cast<const short8*>(&Ash[rbuf][(wr * 64 + mi * 16 + lrow) * 32 + kg]);
#pragma unroll
    for (int ni = 0; ni < 4; ++ni)
      b[ni] = *reinterpret_cast<const short8*>(&Bsh[rbuf][(wc * 64 + ni * 16 + lrow) * 32 + kg]);
#pragma unroll
    for (int mi = 0; mi < 4; ++mi)
#pragma unroll
      for (int ni = 0; ni < 4; ++ni)
        acc[mi][ni] = __builtin_amdgcn_mfma_f32_16x16x32_bf16(a[mi], b[ni], acc[mi][ni], 0, 0, 0);

    rbuf = (rbuf == 2) ? 0 : rbuf + 1;
    sbuf = (sbuf == 2) ? 0 : sbuf + 1;
  }
#undef STAGE

  // Epilogue. C/D layout (m89): col = lane&15, row = (lane>>4)*4 + reg.
  const int rg = (lane >> 4) << 2;
  for (int ni = 0; ni < 4; ++ni) {
    const int col = n0 + wc * 64 + ni * 16 + lrow;
    const float bz = bias[col];
    const int sec = col / 768;  // 0=q 1=k 2=v; uniform per ni (768%16==0)
    const int dh = col & 63;
    const bool odd = dh & 1;
    const int jf = (dh >> 1) & 15;
    const bool usex = (dh >> 1) < 16;
    const float invf = __powf(10000.0f, -(float)jf * (1.0f / 16.0f));
    for (int mi = 0; mi < 4; ++mi) {
      const int rowb = m0 + wr * 64 + mi * 16 + rg;
#pragma unroll
      for (int r = 0; r < 4; ++r) {
        const int row = rowb + r;
        float v = acc[mi][ni][r] + bz;
        if (ROPE && sec != 2) {
          const float partner = __shfl_xor(v, 1);  // pair element (w/ its bias)
          float cs = 1.f, sn = 0.f;
          if (row > 0) {  // uniform within 16-lane group
            const int cl = min(row, kS - 1) - 1;
            const float cx = (float)coords[cl * 2] * 1e-5f;
            const float cy = (float)coords[cl * 2 + 1] * 1e-5f;
            __sincosf((usex ? cx : cy) * invf, &sn, &cs);
          }
          v = odd ? (v * cs + partner * sn) : (v * cs - partner * sn);
          if (sec == 0) v *= kScale;  // q pre-scaled (incl CLS row)
        }
        if (row < Mreal) store_c(&C[(size_t)row * N + col], v);
      }
    }
  }
}

// Fused attention kernel:
//  blocks [0,384):   MFMA patch attention (lattice coords), 4 waves = 4 units
//  blocks [384,768): CLS split-K partials (h = idx>>5, chunk = idx&31)
__global__ __launch_bounds__(256) void attn_kernel(const short* __restrict__ qkv,
                                                   short* __restrict__ attn,
                                                   float* __restrict__ part) {
  __shared__ short Pl[4][32][104];
  __shared__ float sm[4], sl[4], sa[4][64];
  const int lane = threadIdx.x & 63;
  const int wv = threadIdx.x >> 6;

  if (blockIdx.x >= 384) {  // ---------- CLS partial ----------
    const int idx = blockIdx.x - 384;
    const int h = idx >> 5;
    const int c = idx & 31;
    const int start = c * 128;
    const int end = (c == kClsChunks - 1) ? kS : start + 128;
    const float qd = bf2f(qkv[h * kD + lane]);  // scaled q, row 0
    float m = -INFINITY, lsum = 0.f, acc = 0.f;
    for (int s = start + wv; s < end; s += 4) {
      float tt = qd * bf2f(qkv[(size_t)s * kQKVN + kE + h * kD + lane]);
      tt += __shfl_xor(tt, 1); tt += __shfl_xor(tt, 2); tt += __shfl_xor(tt, 4);
      tt += __shfl_xor(tt, 8); tt += __shfl_xor(tt, 16); tt += __shfl_xor(tt, 32);
      const float vd = bf2f(qkv[(size_t)s * kQKVN + 2 * kE + h * kD + lane]);
      const float mnew = fmaxf(m, tt);
      const float cor = __expf(m - mnew);
      const float p = __expf(tt - mnew);
      lsum = lsum * cor + p;
      acc = acc * cor + p * vd;
      m = mnew;
    }
    sa[wv][lane] = acc;
    if (lane == 0) { sm[wv] = m; sl[wv] = lsum; }
    __syncthreads();
    if (wv == 0) {
      float M = fmaxf(fmaxf(sm[0], sm[1]), fmaxf(sm[2], sm[3]));
      float Lt = 0.f, Av = 0.f;
#pragma unroll
      for (int w = 0; w < 4; ++w) {
        const float cw = __expf(sm[w] - M);
        Lt += sl[w] * cw;
        Av += sa[w][lane] * cw;
      }
      float* p = part + ((size_t)h * kClsChunks + c) * kClsStride;
      p[lane] = Av;
      if (lane == 0) { p[64] = M; p[65] = Lt; }
    }
    return;
  }

  // ---------- patch attention ----------
  const int unit = blockIdx.x * 4 + wv;
  const int t0 = (unit & 31) * 32;
  const int res = (unit >> 5) & 3;
  const int h = unit >> 7;
  const int lrow = lane & 15;
  const int lgrp = lane >> 4;
  const int kg = lgrp * 8;
  const int rg = lgrp * 4;

  // ---- QK^T ----
  f32x4 s_acc[2][4] = {};
  f32x4 s_cls[2] = {};
  short8 aq[2][2];
#pragma unroll
  for (int mi = 0; mi < 2; ++mi) {
    const int tq = t0 + mi * 16 + lrow;
    const size_t row = (size_t)(4 * tq + res + 1) * kQKVN + h * kD;
#pragma unroll
    for (int ks = 0; ks < 2; ++ks)
      aq[mi][ks] = *reinterpret_cast<const short8*>(qkv + row + ks * 32 + kg);
  }
#pragma unroll
  for (int ni = 0; ni < 4; ++ni) {
    int u = t0 - 16 + ni * 16 + lrow;
    u = min(max(u, 0), kT - 1);  // clamp; invalid cols masked in softmax
    const size_t row = (size_t)(4 * u + res + 1) * kQKVN + kE + h * kD;
    short8 bk[2];
#pragma unroll
    for (int ks = 0; ks < 2; ++ks)
      bk[ks] = *reinterpret_cast<const short8*>(qkv + row + ks * 32 + kg);
#pragma unroll
    for (int mi = 0; mi < 2; ++mi)
#pragma unroll
      for (int ks = 0; ks < 2; ++ks)
        s_acc[mi][ni] = __builtin_amdgcn_mfma_f32_16x16x32_bf16(aq[mi][ks], bk[ks], s_acc[mi][ni], 0, 0, 0);
  }
  {  // CLS key column
    short8 bc[2] = {};
    if (lrow == 0) {
#pragma unroll
      for (int ks = 0; ks < 2; ++ks)
        bc[ks] = *reinterpret_cast<const short8*>(qkv + kE + h * kD + ks * 32 + kg);
    }
#pragma unroll
    for (int mi = 0; mi < 2; ++mi)
#pragma unroll
      for (int ks = 0; ks < 2; ++ks)
        s_cls[mi] = __builtin_amdgcn_mfma_f32_16x16x32_bf16(aq[mi][ks], bc[ks], s_cls[mi], 0, 0, 0);
  }

  // ---- zero-fill P cols 64..95 ----
#pragma unroll
  for (int i = 0; i < 2; ++i) {
    const int idx = i * 64 + lane;
    const int q = idx >> 2, ch = idx & 3;
    short8 z = {};
    *reinterpret_cast<short8*>(&Pl[wv][q][64 + ch * 8]) = z;
  }

  // ---- softmax per query row (C-layout), write normalized P ----
#pragma unroll
  for (int mi = 0; mi < 2; ++mi) {
#pragma unroll
    for (int r = 0; r < 4; ++r) {
      const int q = mi * 16 + rg + r;
      float sw[4];
      float m = -INFINITY;
#pragma unroll
      for (int ni = 0; ni < 4; ++ni) {
        const int kk = ni * 16 + lrow;
        const int u = t0 - 16 + kk;
        const bool valid = (kk >= q) & (kk <= q + 32) & (u >= 0) & (u < kT);
        sw[ni] = valid ? s_acc[mi][ni][r] : -INFINITY;
        m = fmaxf(m, sw[ni]);
      }
      float scl = (lrow == 0) ? s_cls[mi][r] : -INFINITY;
      m = fmaxf(m, scl);
      m = fmaxf(m, __shfl_xor(m, 1)); m = fmaxf(m, __shfl_xor(m, 2));
      m = fmaxf(m, __shfl_xor(m, 4)); m = fmaxf(m, __shfl_xor(m, 8));
      float lsum = 0.f, ps[4];
#pragma unroll
      for (int ni = 0; ni < 4; ++ni) { ps[ni] = __expf(sw[ni] - m); lsum += ps[ni]; }
      const float pc = __expf(scl - m);
      lsum += pc;
      lsum += __shfl_xor(lsum, 1); lsum += __shfl_xor(lsum, 2);
      lsum += __shfl_xor(lsum, 4); lsum += __shfl_xor(lsum, 8);
      const float inv = __builtin_amdgcn_rcpf(lsum);
#pragma unroll
      for (int ni = 0; ni < 4; ++ni) Pl[wv][q][ni * 16 + lrow] = f2bf(ps[ni] * inv);
      if (lrow == 0) Pl[wv][q][64] = f2bf(pc * inv);
    }
  }

  // ---- PV: out[d][q] += V^T[d][kk] * P[q][kk] ----
  f32x4 o_acc[4][2] = {};
#pragma unroll
  for (int ks = 0; ks < 3; ++ks) {
    short8 bp[2];
#pragma unroll
    for (int nq = 0; nq < 2; ++nq)
      bp[nq] = *reinterpret_cast<const short8*>(&Pl[wv][nq * 16 + lrow][ks * 32 + kg]);
    short8 av[4];
#pragma unroll
    for (int md = 0; md < 4; ++md) {
      if (ks < 2) {
        const int d = md * 16 + lrow;
#pragma unroll
        for (int e = 0; e < 8; ++e) {
          const int kk = ks * 32 + kg + e;
          int u = t0 - 16 + kk;
          u = min(max(u, 0), kT - 1);  // invalid kk have P==0
          av[md][e] = qkv[(size_t)(4 * u + res + 1) * kQKVN + 2 * kE + h * kD + d];
        }
      } else {
        short8 z = {};
        av[md] = z;
        if (lgrp == 0)  // kk==64 -> v_cls
          av[md][0] = qkv[2 * kE + h * kD + md * 16 + lrow];
      }
#pragma unroll
      for (int nq = 0; nq < 2; ++nq)
        o_acc[md][nq] = __builtin_amdgcn_mfma_f32_16x16x32_bf16(av[md], bp[nq], o_acc[md][nq], 0, 0, 0);
    }
  }

  // ---- store ----
#pragma unroll
  for (int md = 0; md < 4; ++md)
#pragma unroll
    for (int nq = 0; nq < 2; ++nq)
#pragma unroll
      for (int r = 0; r < 4; ++r) {
        const int d = md * 16 + rg + r;
        const int q = nq * 16 + lrow;
        const int s = 4 * (t0 + q) + res + 1;
        attn[(size_t)s * kE + h * kD + d] = f2bf(o_acc[md][nq][r]);
      }
}

// CLS attention pass 2: combine 32 partials per head. 12 blocks x 64 lanes.
__global__ __launch_bounds__(64) void cls_combine_kernel(const float* __restrict__ part,
                                                         short* __restrict__ attn) {
  const int h = blockIdx.x;
  const int lane = threadIdx.x;
  float mc[kClsChunks], lc[kClsChunks], ac[kClsChunks];
#pragma unroll
  for (int c = 0; c < kClsChunks; ++c) {
    const float* p = part + ((size_t)h * kClsChunks + c) * kClsStride;
    mc[c] = p[64];
    lc[c] = p[65];
    ac[c] = p[lane];
  }
  float M = -INFINITY;
#pragma unroll
  for (int c = 0; c < kClsChunks; ++c) M = fmaxf(M, mc[c]);
  float L = 0.f, A = 0.f;
#pragma unroll
  for (int c = 0; c < kClsChunks; ++c) {
    const float w = __expf(mc[c] - M);
    L += lc[c] * w;
    A += ac[c] * w;
  }
  attn[h * kD + lane] = f2bf(A / L);
}

}  // namespace

extern "C" void kernel_launch(void* const* d_in, const int* in_sizes, int n_in,
                              void* d_out, int out_size, void* d_ws, size_t ws_size,
                              hipStream_t stream) {
  const float* x = (const float*)d_in[0];
  const int* coords = (const int*)d_in[1];
  const float* qkv_w = (const float*)d_in[2];
  const float* qkv_b = (const float*)d_in[3];
  const float* out_w = (const float*)d_in[4];
  const float* out_b = (const float*)d_in[5];
  float* out = (float*)d_out;

  char* p = (char*)d_ws;
  short* qkvb = (short*)p;                p += (size_t)kS * kQKVN * sizeof(short);  // 18.9 MB
  short* xb = (short*)p;                  p += (size_t)kS * kE * sizeof(short);     // 6.3 MB
  short* wb = (short*)p;                  p += (size_t)kQKVN * kE * sizeof(short);  // 3.5 MB
  short* owb = (short*)p;                 p += (size_t)kE * kE * sizeof(short);     // 1.2 MB
  short* attnb = (short*)p;               p += (size_t)kS * kE * sizeof(short);     // 6.3 MB
  float* clsp = (float*)p;                // 12*32*68 floats = 104 KB

  const int n4x = kS * kE / 4;
  const int n4w = kQKVN * kE / 4;
  const int n4o = kE * kE / 4;
  cvt3_kernel<<<2048, 256, 0, stream>>>(x, qkv_w, out_w, xb, wb, owb, n4x, n4w, n4o);

  dim3 g1(33, 18);  // ceil(4097/128), 2304/128
  gemm_tile_kernel<true, short><<<g1, 256, 0, stream>>>(xb, wb, qkv_b, qkvb, kS, kQKVN, kE, coords);
  attn_kernel<<<768, 256, 0, stream>>>(qkvb, attnb, clsp);
  cls_combine_kernel<<<kH, 64, 0, stream>>>(clsp, attnb);
  dim3 g2(33, 6);   // ceil(4097/128), 768/128
  gemm_tile_kernel<false, float><<<g2, 256, 0, stream>>>(attnb, owb, out_b, out, kS, kE, kE, nullptr);
}

// Round 9
// 101.978 us; speedup vs baseline: 6.1435x; 1.0242x over previous
//
#include <hip/hip_runtime.h>
#include <hip/hip_bf16.h>

namespace {

constexpr int kS = 4097;      // sequence incl. CLS
constexpr int kL = 4096;      // patch tokens
constexpr int kE = 768;
constexpr int kH = 12;
constexpr int kD = 64;
constexpr int kQKVN = 2304;
constexpr int kT = 1024;      // lattice length per residue (kL / kDil)
constexpr int kClsChunks = 32;
constexpr int kClsStride = 68;    // 64 acc + m + l, padded
constexpr float kScale = 0.125f;  // 1/sqrt(64)

typedef short short8 __attribute__((ext_vector_type(8)));
typedef short short4v __attribute__((ext_vector_type(4)));
typedef float f32x4 __attribute__((ext_vector_type(4)));

__device__ inline short f2bf(float x) {
  __hip_bfloat16 b = __float2bfloat16(x);
  return *reinterpret_cast<short*>(&b);
}
__device__ inline float bf2f(short u) {
  unsigned int x = ((unsigned int)(unsigned short)u) << 16;
  union { unsigned int u32; float f; } c;
  c.u32 = x;
  return c.f;
}

__device__ inline void store_c(float* p, float v) { *p = v; }
__device__ inline void store_c(short* p, float v) { *p = f2bf(v); }

// m204 bijective XCD swizzle: consecutive output ids share an XCD.
__device__ inline int xcd_swz(int bid, int nwg) {
  const int q = nwg >> 3, r = nwg & 7;
  const int x = bid & 7, o = bid >> 3;
  return (x < r ? x * (q + 1) : r * (q + 1) + (x - r) * q) + o;
}

// Fused fp32->bf16 convert of x, qkv_w, out_w in one grid-stride kernel.
__global__ __launch_bounds__(256) void cvt3_kernel(const float* __restrict__ x,
                                                   const float* __restrict__ w,
                                                   const float* __restrict__ ow,
                                                   short* __restrict__ xb,
                                                   short* __restrict__ wb,
                                                   short* __restrict__ owb,
                                                   int n4x, int n4w, int n4o) {
  const int total = n4x + n4w + n4o;
  int i = blockIdx.x * blockDim.x + threadIdx.x;
  const int stride = gridDim.x * blockDim.x;
  for (; i < total; i += stride) {
    const float* src;
    short* dst;
    int k;
    if (i < n4x) { src = x; dst = xb; k = i; }
    else if (i < n4x + n4w) { src = w; dst = wb; k = i - n4x; }
    else { src = ow; dst = owb; k = i - n4x - n4w; }
    f32x4 v = reinterpret_cast<const f32x4*>(src)[k];
    short4v o;
#pragma unroll
    for (int j = 0; j < 4; ++j) o[j] = f2bf(v[j]);
    reinterpret_cast<short4v*>(dst)[k] = o;
  }
}

// Reg-staged double-buffered GEMM (T14 async-STAGE):
// C[M][N] = A(bf16)*W(bf16)^T + bias(f32). 128x128 tile, BK=32, 4 waves (2x2),
// 4x4 16x16x32 fragments. Global->reg loads for tile t+1 issued BEFORE the
// compute of tile t (compiler-placed vmcnt at the ds_write hides HBM latency
// under MFMA). Two raw barriers/iter; explicit lgkmcnt(0) before bar2.
// 1D grid with m204 XCD swizzle (ntm m-tiles, x-fastest).
// ROPE: 2D rope + q-scale fused into the QKV-GEMM epilogue.
template <bool ROPE, typename TC>
__global__ __launch_bounds__(256) void gemm_tile_kernel(const short* __restrict__ A,
                                                        const short* __restrict__ W,
                                                        const float* __restrict__ bias,
                                                        TC* __restrict__ C,
                                                        int Mreal, int N, int K, int ntm,
                                                        const int* __restrict__ coords) {
  __shared__ short Ash[2][128 * 32];
  __shared__ short Bsh[2][128 * 32];
  const int nwg = gridDim.x;
  const int wid = xcd_swz(blockIdx.x, nwg);
  const int m0 = (wid % ntm) * 128;
  const int n0 = (wid / ntm) * 128;
  const int t = threadIdx.x;
  const int lane = t & 63;
  const int wave = t >> 6;
  const int wr = wave >> 1, wc = wave & 1;
  const int lrow = lane & 15;
  const int kg = (lane >> 4) << 3;

  const int srow = t >> 2;
  const int scol = (t & 3) << 3;
  int arow0 = m0 + srow;       if (arow0 > Mreal - 1) arow0 = Mreal - 1;
  int arow1 = m0 + 64 + srow;  if (arow1 > Mreal - 1) arow1 = Mreal - 1;
  const int brow0 = n0 + srow;
  const int brow1 = n0 + 64 + srow;

  const short* pa0 = A + (size_t)arow0 * K + scol;
  const short* pa1 = A + (size_t)arow1 * K + scol;
  const short* pb0 = W + (size_t)brow0 * K + scol;
  const short* pb1 = W + (size_t)brow1 * K + scol;

  f32x4 acc[4][4] = {};
  const int nsteps = K / 32;

  // Prologue: stage tile 0 through regs.
  short8 rA0 = *reinterpret_cast<const short8*>(pa0);
  short8 rA1 = *reinterpret_cast<const short8*>(pa1);
  short8 rB0 = *reinterpret_cast<const short8*>(pb0);
  short8 rB1 = *reinterpret_cast<const short8*>(pb1);
  *reinterpret_cast<short8*>(&Ash[0][t * 8]) = rA0;
  *reinterpret_cast<short8*>(&Ash[0][2048 + t * 8]) = rA1;
  *reinterpret_cast<short8*>(&Bsh[0][t * 8]) = rB0;
  *reinterpret_cast<short8*>(&Bsh[0][2048 + t * 8]) = rB1;
  asm volatile("s_waitcnt lgkmcnt(0)" ::: "memory");
  __builtin_amdgcn_s_barrier();
  __builtin_amdgcn_sched_barrier(0);

  int cur = 0;
  for (int tt = 0; tt < nsteps; ++tt) {
    // Issue next tile's global loads FIRST — latency hides under compute below.
    if (tt + 1 < nsteps) {
      const int k1 = (tt + 1) * 32;
      rA0 = *reinterpret_cast<const short8*>(pa0 + k1);
      rA1 = *reinterpret_cast<const short8*>(pa1 + k1);
      rB0 = *reinterpret_cast<const short8*>(pb0 + k1);
      rB1 = *reinterpret_cast<const short8*>(pb1 + k1);
    }

    // Compute tile tt from LDS[cur].
    short8 a[4], b[4];
#pragma unroll
    for (int mi = 0; mi < 4; ++mi)
      a[mi] = *reinterpret_cast<const short8*>(&Ash[cur][(wr * 64 + mi * 16 + lrow) * 32 + kg]);
#pragma unroll
    for (int ni = 0; ni < 4; ++ni)
      b[ni] = *reinterpret_cast<const short8*>(&Bsh[cur][(wc * 64 + ni * 16 + lrow) * 32 + kg]);
#pragma unroll
    for (int mi = 0; mi < 4; ++mi)
#pragma unroll
      for (int ni = 0; ni < 4; ++ni)
        acc[mi][ni] = __builtin_amdgcn_mfma_f32_16x16x32_bf16(a[mi], b[ni], acc[mi][ni], 0, 0, 0);

    __builtin_amdgcn_s_barrier();        // all waves done reading buf cur^1 (2 barriers ago)
    __builtin_amdgcn_sched_barrier(0);

    if (tt + 1 < nsteps) {               // write-late: compiler waits vmcnt here only
      *reinterpret_cast<short8*>(&Ash[cur ^ 1][t * 8]) = rA0;
      *reinterpret_cast<short8*>(&Ash[cur ^ 1][2048 + t * 8]) = rA1;
      *reinterpret_cast<short8*>(&Bsh[cur ^ 1][t * 8]) = rB0;
      *reinterpret_cast<short8*>(&Bsh[cur ^ 1][2048 + t * 8]) = rB1;
    }
    asm volatile("s_waitcnt lgkmcnt(0)" ::: "memory");
    __builtin_amdgcn_sched_barrier(0);
    __builtin_amdgcn_s_barrier();        // buf cur^1 ready for next iter
    __builtin_amdgcn_sched_barrier(0);
    cur ^= 1;
  }

  // Epilogue. C/D layout (m89): col = lane&15, row = (lane>>4)*4 + reg.
  const int rg = (lane >> 4) << 2;
  for (int ni = 0; ni < 4; ++ni) {
    const int col = n0 + wc * 64 + ni * 16 + lrow;
    const float bz = bias[col];
    const int sec = col / 768;  // 0=q 1=k 2=v; uniform per ni (768%16==0)
    const int dh = col & 63;
    const bool odd = dh & 1;
    const int jf = (dh >> 1) & 15;
    const bool usex = (dh >> 1) < 16;
    const float invf = __powf(10000.0f, -(float)jf * (1.0f / 16.0f));
    for (int mi = 0; mi < 4; ++mi) {
      const int rowb = m0 + wr * 64 + mi * 16 + rg;
#pragma unroll
      for (int r = 0; r < 4; ++r) {
        const int row = rowb + r;
        float v = acc[mi][ni][r] + bz;
        if (ROPE && sec != 2) {
          const float partner = __shfl_xor(v, 1);  // pair element (w/ its bias)
          float cs = 1.f, sn = 0.f;
          if (row > 0) {  // uniform within 16-lane group
            const int cl = min(row, kS - 1) - 1;
            const float cx = (float)coords[cl * 2] * 1e-5f;
            const float cy = (float)coords[cl * 2 + 1] * 1e-5f;
            __sincosf((usex ? cx : cy) * invf, &sn, &cs);
          }
          v = odd ? (v * cs + partner * sn) : (v * cs - partner * sn);
          if (sec == 0) v *= kScale;  // q pre-scaled (incl CLS row)
        }
        if (row < Mreal) store_c(&C[(size_t)row * N + col], v);
      }
    }
  }
}

// Fused attention kernel:
//  blocks [0,384):   MFMA patch attention (lattice coords), 4 waves = 4 units
//  blocks [384,768): CLS split-K partials (h = idx>>5, chunk = idx&31)
__global__ __launch_bounds__(256) void attn_kernel(const short* __restrict__ qkv,
                                                   short* __restrict__ attn,
                                                   float* __restrict__ part) {
  __shared__ short Pl[4][32][104];
  __shared__ float sm[4], sl[4], sa[4][64];
  const int lane = threadIdx.x & 63;
  const int wv = threadIdx.x >> 6;

  if (blockIdx.x >= 384) {  // ---------- CLS partial ----------
    const int idx = blockIdx.x - 384;
    const int h = idx >> 5;
    const int c = idx & 31;
    const int start = c * 128;
    const int end = (c == kClsChunks - 1) ? kS : start + 128;
    const float qd = bf2f(qkv[h * kD + lane]);  // scaled q, row 0
    float m = -INFINITY, lsum = 0.f, acc = 0.f;
    for (int s = start + wv; s < end; s += 4) {
      float tt = qd * bf2f(qkv[(size_t)s * kQKVN + kE + h * kD + lane]);
      tt += __shfl_xor(tt, 1); tt += __shfl_xor(tt, 2); tt += __shfl_xor(tt, 4);
      tt += __shfl_xor(tt, 8); tt += __shfl_xor(tt, 16); tt += __shfl_xor(tt, 32);
      const float vd = bf2f(qkv[(size_t)s * kQKVN + 2 * kE + h * kD + lane]);
      const float mnew = fmaxf(m, tt);
      const float cor = __expf(m - mnew);
      const float p = __expf(tt - mnew);
      lsum = lsum * cor + p;
      acc = acc * cor + p * vd;
      m = mnew;
    }
    sa[wv][lane] = acc;
    if (lane == 0) { sm[wv] = m; sl[wv] = lsum; }
    __syncthreads();
    if (wv == 0) {
      float M = fmaxf(fmaxf(sm[0], sm[1]), fmaxf(sm[2], sm[3]));
      float Lt = 0.f, Av = 0.f;
#pragma unroll
      for (int w = 0; w < 4; ++w) {
        const float cw = __expf(sm[w] - M);
        Lt += sl[w] * cw;
        Av += sa[w][lane] * cw;
      }
      float* p = part + ((size_t)h * kClsChunks + c) * kClsStride;
      p[lane] = Av;
      if (lane == 0) { p[64] = M; p[65] = Lt; }
    }
    return;
  }

  // ---------- patch attention ----------
  const int unit = blockIdx.x * 4 + wv;
  const int t0 = (unit & 31) * 32;
  const int res = (unit >> 5) & 3;
  const int h = unit >> 7;
  const int lrow = lane & 15;
  const int lgrp = lane >> 4;
  const int kg = lgrp * 8;
  const int rg = lgrp * 4;

  // ---- QK^T ----
  f32x4 s_acc[2][4] = {};
  f32x4 s_cls[2] = {};
  short8 aq[2][2];
#pragma unroll
  for (int mi = 0; mi < 2; ++mi) {
    const int tq = t0 + mi * 16 + lrow;
    const size_t row = (size_t)(4 * tq + res + 1) * kQKVN + h * kD;
#pragma unroll
    for (int ks = 0; ks < 2; ++ks)
      aq[mi][ks] = *reinterpret_cast<const short8*>(qkv + row + ks * 32 + kg);
  }
#pragma unroll
  for (int ni = 0; ni < 4; ++ni) {
    int u = t0 - 16 + ni * 16 + lrow;
    u = min(max(u, 0), kT - 1);  // clamp; invalid cols masked in softmax
    const size_t row = (size_t)(4 * u + res + 1) * kQKVN + kE + h * kD;
    short8 bk[2];
#pragma unroll
    for (int ks = 0; ks < 2; ++ks)
      bk[ks] = *reinterpret_cast<const short8*>(qkv + row + ks * 32 + kg);
#pragma unroll
    for (int mi = 0; mi < 2; ++mi)
#pragma unroll
      for (int ks = 0; ks < 2; ++ks)
        s_acc[mi][ni] = __builtin_amdgcn_mfma_f32_16x16x32_bf16(aq[mi][ks], bk[ks], s_acc[mi][ni], 0, 0, 0);
  }
  {  // CLS key column
    short8 bc[2] = {};
    if (lrow == 0) {
#pragma unroll
      for (int ks = 0; ks < 2; ++ks)
        bc[ks] = *reinterpret_cast<const short8*>(qkv + kE + h * kD + ks * 32 + kg);
    }
#pragma unroll
    for (int mi = 0; mi < 2; ++mi)
#pragma unroll
      for (int ks = 0; ks < 2; ++ks)
        s_cls[mi] = __builtin_amdgcn_mfma_f32_16x16x32_bf16(aq[mi][ks], bc[ks], s_cls[mi], 0, 0, 0);
  }

  // ---- zero-fill P cols 64..95 ----
#pragma unroll
  for (int i = 0; i < 2; ++i) {
    const int idx = i * 64 + lane;
    const int q = idx >> 2, ch = idx & 3;
    short8 z = {};
    *reinterpret_cast<short8*>(&Pl[wv][q][64 + ch * 8]) = z;
  }

  // ---- softmax per query row (C-layout), write normalized P ----
#pragma unroll
  for (int mi = 0; mi < 2; ++mi) {
#pragma unroll
    for (int r = 0; r < 4; ++r) {
      const int q = mi * 16 + rg + r;
      float sw[4];
      float m = -INFINITY;
#pragma unroll
      for (int ni = 0; ni < 4; ++ni) {
        const int kk = ni * 16 + lrow;
        const int u = t0 - 16 + kk;
        const bool valid = (kk >= q) & (kk <= q + 32) & (u >= 0) & (u < kT);
        sw[ni] = valid ? s_acc[mi][ni][r] : -INFINITY;
        m = fmaxf(m, sw[ni]);
      }
      float scl = (lrow == 0) ? s_cls[mi][r] : -INFINITY;
      m = fmaxf(m, scl);
      m = fmaxf(m, __shfl_xor(m, 1)); m = fmaxf(m, __shfl_xor(m, 2));
      m = fmaxf(m, __shfl_xor(m, 4)); m = fmaxf(m, __shfl_xor(m, 8));
      float lsum = 0.f, ps[4];
#pragma unroll
      for (int ni = 0; ni < 4; ++ni) { ps[ni] = __expf(sw[ni] - m); lsum += ps[ni]; }
      const float pc = __expf(scl - m);
      lsum += pc;
      lsum += __shfl_xor(lsum, 1); lsum += __shfl_xor(lsum, 2);
      lsum += __shfl_xor(lsum, 4); lsum += __shfl_xor(lsum, 8);
      const float inv = __builtin_amdgcn_rcpf(lsum);
#pragma unroll
      for (int ni = 0; ni < 4; ++ni) Pl[wv][q][ni * 16 + lrow] = f2bf(ps[ni] * inv);
      if (lrow == 0) Pl[wv][q][64] = f2bf(pc * inv);
    }
  }

  // ---- PV: out[d][q] += V^T[d][kk] * P[q][kk] ----
  f32x4 o_acc[4][2] = {};
#pragma unroll
  for (int ks = 0; ks < 3; ++ks) {
    short8 bp[2];
#pragma unroll
    for (int nq = 0; nq < 2; ++nq)
      bp[nq] = *reinterpret_cast<const short8*>(&Pl[wv][nq * 16 + lrow][ks * 32 + kg]);
    short8 av[4];
#pragma unroll
    for (int md = 0; md < 4; ++md) {
      if (ks < 2) {
        const int d = md * 16 + lrow;
#pragma unroll
        for (int e = 0; e < 8; ++e) {
          const int kk = ks * 32 + kg + e;
          int u = t0 - 16 + kk;
          u = min(max(u, 0), kT - 1);  // invalid kk have P==0
          av[md][e] = qkv[(size_t)(4 * u + res + 1) * kQKVN + 2 * kE + h * kD + d];
        }
      } else {
        short8 z = {};
        av[md] = z;
        if (lgrp == 0)  // kk==64 -> v_cls
          av[md][0] = qkv[2 * kE + h * kD + md * 16 + lrow];
      }
#pragma unroll
      for (int nq = 0; nq < 2; ++nq)
        o_acc[md][nq] = __builtin_amdgcn_mfma_f32_16x16x32_bf16(av[md], bp[nq], o_acc[md][nq], 0, 0, 0);
    }
  }

  // ---- store ----
#pragma unroll
  for (int md = 0; md < 4; ++md)
#pragma unroll
    for (int nq = 0; nq < 2; ++nq)
#pragma unroll
      for (int r = 0; r < 4; ++r) {
        const int d = md * 16 + rg + r;
        const int q = nq * 16 + lrow;
        const int s = 4 * (t0 + q) + res + 1;
        attn[(size_t)s * kE + h * kD + d] = f2bf(o_acc[md][nq][r]);
      }
}

// CLS attention pass 2: combine 32 partials per head. 12 blocks x 64 lanes.
__global__ __launch_bounds__(64) void cls_combine_kernel(const float* __restrict__ part,
                                                         short* __restrict__ attn) {
  const int h = blockIdx.x;
  const int lane = threadIdx.x;
  float mc[kClsChunks], lc[kClsChunks], ac[kClsChunks];
#pragma unroll
  for (int c = 0; c < kClsChunks; ++c) {
    const float* p = part + ((size_t)h * kClsChunks + c) * kClsStride;
    mc[c] = p[64];
    lc[c] = p[65];
    ac[c] = p[lane];
  }
  float M = -INFINITY;
#pragma unroll
  for (int c = 0; c < kClsChunks; ++c) M = fmaxf(M, mc[c]);
  float L = 0.f, A = 0.f;
#pragma unroll
  for (int c = 0; c < kClsChunks; ++c) {
    const float w = __expf(mc[c] - M);
    L += lc[c] * w;
    A += ac[c] * w;
  }
  attn[h * kD + lane] = f2bf(A / L);
}

}  // namespace

extern "C" void kernel_launch(void* const* d_in, const int* in_sizes, int n_in,
                              void* d_out, int out_size, void* d_ws, size_t ws_size,
                              hipStream_t stream) {
  const float* x = (const float*)d_in[0];
  const int* coords = (const int*)d_in[1];
  const float* qkv_w = (const float*)d_in[2];
  const float* qkv_b = (const float*)d_in[3];
  const float* out_w = (const float*)d_in[4];
  const float* out_b = (const float*)d_in[5];
  float* out = (float*)d_out;

  char* p = (char*)d_ws;
  short* qkvb = (short*)p;                p += (size_t)kS * kQKVN * sizeof(short);  // 18.9 MB
  short* xb = (short*)p;                  p += (size_t)kS * kE * sizeof(short);     // 6.3 MB
  short* wb = (short*)p;                  p += (size_t)kQKVN * kE * sizeof(short);  // 3.5 MB
  short* owb = (short*)p;                 p += (size_t)kE * kE * sizeof(short);     // 1.2 MB
  short* attnb = (short*)p;               p += (size_t)kS * kE * sizeof(short);     // 6.3 MB
  float* clsp = (float*)p;                // 12*32*68 floats = 104 KB

  const int n4x = kS * kE / 4;
  const int n4w = kQKVN * kE / 4;
  const int n4o = kE * kE / 4;
  cvt3_kernel<<<2048, 256, 0, stream>>>(x, qkv_w, out_w, xb, wb, owb, n4x, n4w, n4o);

  // gemm1: 33 m-tiles x 18 n-tiles = 594 blocks (1D, XCD-swizzled)
  gemm_tile_kernel<true, short><<<594, 256, 0, stream>>>(xb, wb, qkv_b, qkvb, kS, kQKVN, kE, 33, coords);
  attn_kernel<<<768, 256, 0, stream>>>(qkvb, attnb, clsp);
  cls_combine_kernel<<<kH, 64, 0, stream>>>(clsp, attnb);
  // gemm2: 33 x 6 = 198 blocks
  gemm_tile_kernel<false, float><<<198, 256, 0, stream>>>(attnb, owb, out_b, out, kS, kE, kE, 33, nullptr);
}